// Round 5
// baseline (11507.649 us; speedup 1.0000x reference)
//
#include <hip/hip_runtime.h>
#include <hip/hip_bf16.h>

typedef __attribute__((ext_vector_type(4))) float f32x4;
typedef __attribute__((ext_vector_type(8))) short s16x8;

static constexpr int kB    = 2;
static constexpr int kSTXT = 226;
static constexpr int kSVID = 2048;
static constexpr int kD    = 1024;
static constexpr int kS    = kSTXT + kSVID;   // 2274
static constexpr int kBS   = kB * kS;         // 4548
static constexpr int kSPAD = 2304;            // 36*64 = 72*32
static constexpr int kNT   = kSPAD / 32;      // 72

static __device__ __forceinline__ ushort f2bf(float f) {
  unsigned u = __float_as_uint(f);
  u += 0x7fffu + ((u >> 16) & 1u);            // RNE (finite data only)
  return (ushort)(u >> 16);
}
static __device__ __forceinline__ float bf2f(short x) {
  return __uint_as_float(((unsigned)(ushort)x) << 16);
}

// ---------------- VALU GEMM1: Y[row][n] = X[row]·W[n] ----------------
__global__ __launch_bounds__(256) void k_gemm1_valu(const float* __restrict__ enc, const float* __restrict__ hid,
                                                    const float* __restrict__ wq, const float* __restrict__ wk,
                                                    const float* __restrict__ wv, float* __restrict__ Y) {
  int gw = blockIdx.x * 4 + (threadIdx.x >> 6);   // [0, 48*4548)
  int l = threadIdx.x & 63;
  int chunk = gw / kBS;                            // [0,48)
  int row = gw - chunk * kBS;                      // [0,4548)
  int b = row / kS, s = row - b * kS;
  const float* xr = (s < kSTXT) ? enc + (size_t)(b * kSTXT + s) * kD
                                : hid + (size_t)(b * kSVID + (s - kSTXT)) * kD;
  int wsel = chunk >> 4;
  const float* wb = (wsel == 0) ? wq : (wsel == 1) ? wk : wv;
  const float* wr = wb + (size_t)((chunk & 15) * 64 + l) * kD;
  float acc = 0.0f;
  for (int k0 = 0; k0 < kD; k0 += 4) {
    float4 a = *(const float4*)(xr + k0);
    float4 ww = *(const float4*)(wr + k0);
    acc += a.x * ww.x + a.y * ww.y + a.z * ww.z + a.w * ww.w;
  }
  Y[(size_t)row * 3072 + chunk * 64 + l] = acc;
}

// ---------------- bias + per-head LN + RoPE -> Q/K/V bf16 panels [BH][SPAD][64] ----------------
__global__ __launch_bounds__(256) void k_lnrope(const float* __restrict__ Y,
    const float* __restrict__ bq, const float* __restrict__ bk, const float* __restrict__ bv,
    const float* __restrict__ lnqw, const float* __restrict__ lnqb,
    const float* __restrict__ lnkw, const float* __restrict__ lnkb,
    const float* __restrict__ cosb, const float* __restrict__ sinb,
    ushort* __restrict__ Qo, ushort* __restrict__ Ko, ushort* __restrict__ Vo) {
  int wid = (blockIdx.x * 256 + threadIdx.x) >> 6;   // [0, 32*2304)
  int l = threadIdx.x & 63;
  int bh = wid / kSPAD;
  int s = wid - bh * kSPAD;
  size_t po = (size_t)wid * 64 + l;
  if (s >= kS) { Qo[po] = 0; Ko[po] = 0; Vo[po] = 0; return; }
  int b = bh >> 4, h = bh & 15;
  int row = b * kS + s;
  int col = h * 64 + l;
  const float* yr = Y + (size_t)row * 3072;
  float q = yr[col] + bq[col];
  float k = yr[1024 + col] + bk[col];
  float v = yr[2048 + col] + bv[col];
  float sq = q, sk = k;
#pragma unroll
  for (int m = 1; m < 64; m <<= 1) { sq += __shfl_xor(sq, m); sk += __shfl_xor(sk, m); }
  float dq = q - sq * (1.0f / 64.0f);
  float dk = k - sk * (1.0f / 64.0f);
  float vq = dq * dq, vk = dk * dk;
#pragma unroll
  for (int m = 1; m < 64; m <<= 1) { vq += __shfl_xor(vq, m); vk += __shfl_xor(vk, m); }
  q = dq * rsqrtf(vq * (1.0f / 64.0f) + 1e-5f) * lnqw[l] + lnqb[l];
  k = dk * rsqrtf(vk * (1.0f / 64.0f) + 1e-5f) * lnkw[l] + lnkb[l];
  if (s >= kSTXT) {                              // RoPE on video tokens
    int pos = s - kSTXT;
    float c = cosb[pos * 64 + l], sn = sinb[pos * 64 + l];
    float qp = __shfl_xor(q, 1), kp = __shfl_xor(k, 1);
    float sg = (l & 1) ? 1.0f : -1.0f;
    q = q * c + sg * qp * sn;
    k = k * c + sg * kp * sn;
  }
  Qo[po] = f2bf(q); Ko[po] = f2bf(k); Vo[po] = f2bf(v);
}

// ---------------- VALU flash attention ----------------
__global__ __launch_bounds__(256) void k_attn_valu(const ushort* __restrict__ Q, const ushort* __restrict__ K,
                                                   const ushort* __restrict__ V, ushort* __restrict__ AO) {
  __shared__ float Qt[64][68];
  __shared__ float Kt[32][68];
  __shared__ float Vt[32][68];

  int bid = blockIdx.x;
  int bh = bid / 36, qb = bid - bh * 36;
  const ushort* Qp = Q + (size_t)bh * kSPAD * 64;
  const ushort* Kp = K + (size_t)bh * kSPAD * 64;
  const ushort* Vp = V + (size_t)bh * kSPAD * 64;
  int q0 = qb * 64;

  int tid = threadIdx.x, w = tid >> 6, l = tid & 63;
  int lr = l & 15, lh = l >> 4;
  int myrow = w * 16 + lr;

  {  // stage Q tile (64 rows x 64 dh) as f32
    int row = tid >> 2, seg = tid & 3;
    s16x8 v0 = *(const s16x8*)(Qp + (size_t)(q0 + row) * 64 + seg * 16);
    s16x8 v1 = *(const s16x8*)(Qp + (size_t)(q0 + row) * 64 + seg * 16 + 8);
#pragma unroll
    for (int j = 0; j < 8; ++j) {
      Qt[row][seg * 16 + j] = bf2f(v0[j]);
      Qt[row][seg * 16 + 8 + j] = bf2f(v1[j]);
    }
  }

  float o[16];
#pragma unroll
  for (int c = 0; c < 16; ++c) o[c] = 0.0f;
  float m = -1e30f, lsum = 0.0f;
  const float sc = 0.125f * 1.4426950408889634f;

  for (int t = 0; t < kNT; ++t) {
    int kv0 = t * 32;
    __syncthreads();
    {
      int kv = tid >> 3, seg = tid & 7;
      s16x8 k8 = *(const s16x8*)(Kp + (size_t)(kv0 + kv) * 64 + seg * 8);
      s16x8 v8 = *(const s16x8*)(Vp + (size_t)(kv0 + kv) * 64 + seg * 8);
#pragma unroll
      for (int j = 0; j < 8; ++j) {
        Kt[kv][seg * 8 + j] = bf2f(k8[j]);
        Vt[kv][seg * 8 + j] = bf2f(v8[j]);
      }
    }
    __syncthreads();

    float s8[8];
#pragma unroll
    for (int j = 0; j < 8; ++j) s8[j] = 0.0f;
    for (int dh0 = 0; dh0 < 64; dh0 += 4) {
      float4 q4 = *(const float4*)&Qt[myrow][dh0];
#pragma unroll
      for (int j = 0; j < 8; ++j) {
        float4 k4 = *(const float4*)&Kt[lh * 8 + j][dh0];
        s8[j] += q4.x * k4.x + q4.y * k4.y + q4.z * k4.z + q4.w * k4.w;
      }
    }
#pragma unroll
    for (int j = 0; j < 8; ++j) {
      int kvg = kv0 + lh * 8 + j;
      s8[j] = (kvg >= kS) ? -1e30f : s8[j] * sc;
    }
    float pm = s8[0];
#pragma unroll
    for (int j = 1; j < 8; ++j) pm = fmaxf(pm, s8[j]);
    pm = fmaxf(pm, __shfl_xor(pm, 16));
    pm = fmaxf(pm, __shfl_xor(pm, 32));
    float nm = fmaxf(m, pm);
    float al = exp2f(m - nm);
    m = nm;
    float rs = 0.0f;
#pragma unroll
    for (int j = 0; j < 8; ++j) { s8[j] = exp2f(s8[j] - nm); rs += s8[j]; }
    rs += __shfl_xor(rs, 16);
    rs += __shfl_xor(rs, 32);
    lsum = lsum * al + rs;
#pragma unroll
    for (int c = 0; c < 16; ++c) o[c] *= al;
#pragma unroll
    for (int sl = 0; sl < 4; ++sl) {
#pragma unroll
      for (int j = 0; j < 8; ++j) {
        float p = __shfl(s8[j], sl * 16 + lr);
        const float* vrow = &Vt[sl * 8 + j][lh * 16];
#pragma unroll
        for (int c4 = 0; c4 < 4; ++c4) {
          float4 v4 = *(const float4*)(vrow + c4 * 4);
          o[c4 * 4 + 0] += p * v4.x;
          o[c4 * 4 + 1] += p * v4.y;
          o[c4 * 4 + 2] += p * v4.z;
          o[c4 * 4 + 3] += p * v4.w;
        }
      }
    }
  }

  int b = bh >> 4, h = bh & 15;
  int srow = q0 + myrow;
  if (srow < kS) {
    float inv = 1.0f / lsum;
#pragma unroll
    for (int c = 0; c < 16; ++c)
      AO[(size_t)(b * kS + srow) * kD + h * 64 + lh * 16 + c] = f2bf(o[c] * inv);
  }
}

// ---------------- VALU GEMM2: out = AO·wo^T + bo, permuted (video-first) *** F32 *** store ----------------
__global__ __launch_bounds__(256) void k_gemm2_valu(const ushort* __restrict__ AO, const float* __restrict__ wo,
                                                    const float* __restrict__ bo, float* __restrict__ out) {
  int gw = blockIdx.x * 4 + (threadIdx.x >> 6);   // [0, 16*4548)
  int l = threadIdx.x & 63;
  int chunk = gw / kBS;
  int row = gw - chunk * kBS;
  int n = chunk * 64 + l;
  const ushort* ar = AO + (size_t)row * kD;
  const float* wr = wo + (size_t)n * kD;
  float acc = 0.0f;
  for (int k0 = 0; k0 < kD; k0 += 8) {
    s16x8 a8 = *(const s16x8*)(ar + k0);
    float4 w0 = *(const float4*)(wr + k0);
    float4 w1 = *(const float4*)(wr + k0 + 4);
    acc += bf2f(a8[0]) * w0.x + bf2f(a8[1]) * w0.y + bf2f(a8[2]) * w0.z + bf2f(a8[3]) * w0.w;
    acc += bf2f(a8[4]) * w1.x + bf2f(a8[5]) * w1.y + bf2f(a8[6]) * w1.z + bf2f(a8[7]) * w1.w;
  }
  acc += bo[n];
  int b = row / kS, s = row - b * kS;
  size_t o = (s >= kSTXT) ? ((size_t)(b * kSVID + s - kSTXT) * kD + n)
                          : ((size_t)kB * kSVID * kD + (size_t)(b * kSTXT + s) * kD + n);
  out[o] = acc;                                    // f32 output
}

// ---------------- launch ----------------
extern "C" void kernel_launch(void* const* d_in, const int* in_sizes, int n_in,
                              void* d_out, int out_size, void* d_ws, size_t ws_size,
                              hipStream_t stream) {
  const float* hid  = (const float*)d_in[0];
  const float* enc  = (const float*)d_in[1];
  const float* cosb = (const float*)d_in[2];
  const float* sinb = (const float*)d_in[3];
  const float* wq   = (const float*)d_in[4];
  const float* bq   = (const float*)d_in[5];
  const float* wk   = (const float*)d_in[6];
  const float* bk   = (const float*)d_in[7];
  const float* wv   = (const float*)d_in[8];
  const float* bv   = (const float*)d_in[9];
  const float* wo   = (const float*)d_in[10];
  const float* bo   = (const float*)d_in[11];
  const float* lnqw = (const float*)d_in[12];
  const float* lnqb = (const float*)d_in[13];
  const float* lnkw = (const float*)d_in[14];
  const float* lnkb = (const float*)d_in[15];

  if (ws_size < 112197632u) return;

  char* ws = (char*)d_ws;
  float*  Y    = (float*)(ws + 17825792);        // [4548(+pad)][3072] f32
  ushort* Qb   = (ushort*)(ws + 74448896);       // [32][2304][64] bf16
  ushort* Kb   = (ushort*)(ws + 83886080);
  ushort* Vb   = (ushort*)(ws + 93323264);
  ushort* AO   = (ushort*)(ws + 102760448);      // [4548(+pad)][1024] bf16

  float* out = (float*)d_out;

  k_gemm1_valu<<<dim3(54576), dim3(256), 0, stream>>>(enc, hid, wq, wk, wv, Y);
  k_lnrope<<<dim3(18432), dim3(256), 0, stream>>>(Y, bq, bk, bv, lnqw, lnqb, lnkw, lnkb, cosb, sinb, Qb, Kb, Vb);
  k_attn_valu<<<dim3(1152), dim3(256), 0, stream>>>(Qb, Kb, Vb, AO);
  k_gemm2_valu<<<dim3(18192), dim3(256), 0, stream>>>(AO, wo, bo, out);
}

// Round 6
// 377.802 us; speedup vs baseline: 30.4595x; 30.4595x over previous
//
#include <hip/hip_runtime.h>
#include <hip/hip_bf16.h>

typedef __attribute__((ext_vector_type(4))) float f32x4;
typedef __attribute__((ext_vector_type(8))) short s16x8;
typedef __attribute__((ext_vector_type(4))) short s16x4;

#define GLOAD16(g, s) __builtin_amdgcn_global_load_lds((const __attribute__((address_space(1))) void*)(g), (__attribute__((address_space(3))) void*)(s), 16, 0, 0)

static constexpr int kB    = 2;
static constexpr int kSTXT = 226;
static constexpr int kSVID = 2048;
static constexpr int kD    = 1024;
static constexpr int kS    = kSTXT + kSVID;   // 2274
static constexpr int kBS   = kB * kS;         // 4548
static constexpr int kMPAD = 4608;            // 36*128
static constexpr int kSPAD = 2304;            // 36*64 = 72*32
static constexpr int kNT   = kSPAD / 32;      // 72

static __device__ __forceinline__ ushort f2bf(float f) {
  unsigned u = __float_as_uint(f);
  u += 0x7fffu + ((u >> 16) & 1u);            // RNE (finite data only)
  return (ushort)(u >> 16);
}

static __device__ __forceinline__ f32x4 mfma16(s16x8 a, s16x8 b, f32x4 c) {
  return __builtin_amdgcn_mfma_f32_16x16x32_bf16(a, b, c, 0, 0, 0);
}

// ---------------- prep: weights -> bf16 ----------------
__global__ __launch_bounds__(256) void k_prep_w(const float* __restrict__ wq, const float* __restrict__ wk,
                                                const float* __restrict__ wv, const float* __restrict__ wo,
                                                ushort* __restrict__ Wqkv, ushort* __restrict__ Wo) {
  int q = blockIdx.x * 256 + threadIdx.x;       // quad id, 1048576 total
  int reg = q >> 18;                            // 262144 quads per 1M-elem region
  int off = (q & 262143) << 2;
  const float* sp = (reg == 0) ? wq : (reg == 1) ? wk : (reg == 2) ? wv : wo;
  float4 v = *(const float4*)(sp + off);
  ushort4 o;
  o.x = f2bf(v.x); o.y = f2bf(v.y); o.z = f2bf(v.z); o.w = f2bf(v.w);
  ushort* dst = (reg < 3) ? (Wqkv + ((size_t)reg << 20) + off) : (Wo + off);
  *(ushort4*)dst = o;
}

// ---------------- prep: X concat+cast, zero AO pad rows ----------------
__global__ __launch_bounds__(256) void k_prep_x(const float* __restrict__ hid, const float* __restrict__ enc,
                                                ushort* __restrict__ Xb, ushort* __restrict__ AO) {
  int q = blockIdx.x * 256 + threadIdx.x;
  const int XQ = (kMPAD * kD) / 4;              // 1179648
  if (q < XQ) {
    int row = q >> 8;
    int cq = (q & 255) << 2;
    ushort4 o;
    if (row < kBS) {
      int b = row / kS, s = row - b * kS;
      const float* src = (s < kSTXT) ? (enc + (size_t)(b * kSTXT + s) * kD + cq)
                                     : (hid + (size_t)(b * kSVID + (s - kSTXT)) * kD + cq);
      float4 v = *(const float4*)src;
      o.x = f2bf(v.x); o.y = f2bf(v.y); o.z = f2bf(v.z); o.w = f2bf(v.w);
    } else {
      o.x = 0; o.y = 0; o.z = 0; o.w = 0;
    }
    *(ushort4*)(Xb + (size_t)row * kD + cq) = o;
  } else {
    int p = q - XQ;                             // AO pad: 60 rows * 1024 / 4 = 15360 quads
    ushort4 z; z.x = 0; z.y = 0; z.z = 0; z.w = 0;
    *(ushort4*)(AO + (size_t)kBS * kD + (size_t)p * 4) = z;
  }
}

// ---------------- bf16 GEMM, C = A * B^T  (A[M,K], B[N,K] row-major) ----------------
// EPI==0: write f32 C.  EPI==1: +bias, permuted (video-first) f32 store to out.
template<int EPI>
__global__ __launch_bounds__(256) void k_gemm(const ushort* __restrict__ A, const ushort* __restrict__ Bm,
                                              float* __restrict__ C, float* __restrict__ OutF,
                                              const float* __restrict__ bias, int N, int K) {
  __shared__ ushort lsA[4096];
  __shared__ ushort lsB[4096];
  int nt = N >> 7;
  int mt = blockIdx.x / nt, ntl = blockIdx.x - mt * nt;
  int m0 = mt << 7, n0 = ntl << 7;
  int tid = threadIdx.x;
  int w = tid >> 6, l = tid & 63;
  int wm = (w >> 1) << 6, wn = (w & 1) << 6;
  int lr = l & 15, lh = l >> 4;

  f32x4 acc[4][4] = {};

  for (int k0 = 0; k0 < K; k0 += 32) {
    __syncthreads();
#pragma unroll
    for (int i = 0; i < 2; ++i) {
      int c = i * 256 + w * 64 + l;             // 16B chunk id; row = c>>2, col8 = (c&3)*8
      GLOAD16(A + (size_t)(m0 + (c >> 2)) * K + k0 + ((c & 3) << 3),
              lsA + ((size_t)(i * 256 + w * 64) << 3));
      GLOAD16(Bm + (size_t)(n0 + (c >> 2)) * K + k0 + ((c & 3) << 3),
              lsB + ((size_t)(i * 256 + w * 64) << 3));
    }
    __syncthreads();
    s16x8 af[4], bfr[4];
#pragma unroll
    for (int mi = 0; mi < 4; ++mi) af[mi] = *(const s16x8*)&lsA[(wm + mi * 16 + lr) * 32 + lh * 8];
#pragma unroll
    for (int ni = 0; ni < 4; ++ni) bfr[ni] = *(const s16x8*)&lsB[(wn + ni * 16 + lr) * 32 + lh * 8];
#pragma unroll
    for (int mi = 0; mi < 4; ++mi)
#pragma unroll
      for (int ni = 0; ni < 4; ++ni)
        acc[mi][ni] = mfma16(af[mi], bfr[ni], acc[mi][ni]);
  }

#pragma unroll
  for (int mi = 0; mi < 4; ++mi) {
#pragma unroll
    for (int ni = 0; ni < 4; ++ni) {
#pragma unroll
      for (int r = 0; r < 4; ++r) {
        int row = m0 + wm + mi * 16 + lh * 4 + r;
        int col = n0 + wn + ni * 16 + lr;
        if (EPI == 0) {
          C[(size_t)row * N + col] = acc[mi][ni][r];
        } else {
          if (row < kBS) {
            float v = acc[mi][ni][r] + bias[col];
            int b = row / kS, s = row - b * kS;
            size_t o = (s >= kSTXT) ? ((size_t)(b * kSVID + s - kSTXT) * kD + col)
                                    : ((size_t)kB * kSVID * kD + (size_t)(b * kSTXT + s) * kD + col);
            OutF[o] = v;                         // f32 output (round-5 fix)
          }
        }
      }
    }
  }
}

// ---------------- bias + per-head LN + RoPE -> Q/K/V bf16 panels [BH][SPAD][64] ----------------
__global__ __launch_bounds__(256) void k_lnrope(const float* __restrict__ Y,
    const float* __restrict__ bq, const float* __restrict__ bk, const float* __restrict__ bv,
    const float* __restrict__ lnqw, const float* __restrict__ lnqb,
    const float* __restrict__ lnkw, const float* __restrict__ lnkb,
    const float* __restrict__ cosb, const float* __restrict__ sinb,
    ushort* __restrict__ Qo, ushort* __restrict__ Ko, ushort* __restrict__ Vo) {
  int wid = (blockIdx.x * 256 + threadIdx.x) >> 6;   // [0, 32*2304)
  int l = threadIdx.x & 63;
  int bh = wid / kSPAD;
  int s = wid - bh * kSPAD;
  size_t po = (size_t)wid * 64 + l;
  if (s >= kS) { Qo[po] = 0; Ko[po] = 0; Vo[po] = 0; return; }
  int b = bh >> 4, h = bh & 15;
  int row = b * kS + s;
  int col = h * 64 + l;
  const float* yr = Y + (size_t)row * 3072;
  float q = yr[col] + bq[col];
  float k = yr[1024 + col] + bk[col];
  float v = yr[2048 + col] + bv[col];
  float sq = q, sk = k;
#pragma unroll
  for (int m = 1; m < 64; m <<= 1) { sq += __shfl_xor(sq, m); sk += __shfl_xor(sk, m); }
  float dq = q - sq * (1.0f / 64.0f);
  float dk = k - sk * (1.0f / 64.0f);
  float vq = dq * dq, vk = dk * dk;
#pragma unroll
  for (int m = 1; m < 64; m <<= 1) { vq += __shfl_xor(vq, m); vk += __shfl_xor(vk, m); }
  q = dq * rsqrtf(vq * (1.0f / 64.0f) + 1e-5f) * lnqw[l] + lnqb[l];
  k = dk * rsqrtf(vk * (1.0f / 64.0f) + 1e-5f) * lnkw[l] + lnkb[l];
  if (s >= kSTXT) {                              // RoPE on video tokens
    int pos = s - kSTXT;
    float c = cosb[pos * 64 + l], sn = sinb[pos * 64 + l];
    float qp = __shfl_xor(q, 1), kp = __shfl_xor(k, 1);
    float sg = (l & 1) ? 1.0f : -1.0f;
    q = q * c + sg * qp * sn;
    k = k * c + sg * kp * sn;
  }
  Qo[po] = f2bf(q); Ko[po] = f2bf(k); Vo[po] = f2bf(v);
}

// ---------------- flash attention ----------------
// grid 32*36 blocks, 4 waves; wave = 16 q rows; KV tile = 32 rows
__global__ __launch_bounds__(256) void k_attn(const ushort* __restrict__ Q, const ushort* __restrict__ K,
                                              const ushort* __restrict__ V, ushort* __restrict__ AO) {
  __shared__ ushort lsK[32 * 64];      // XOR-swizzled content
  __shared__ ushort lsVt[64 * 40];     // V^T, row stride 40 elems (conflict-free b128 reads)
  __shared__ ushort lsP[4][16 * 40];   // per-wave P tile, row stride 40

  int bid = blockIdx.x;
  int wg = (bid & 7) * 144 + (bid >> 3);         // XCD swizzle (1152 % 8 == 0 -> bijective)
  int bh = wg / 36, qb = wg - bh * 36;
  const ushort* Qp = Q + (size_t)bh * kSPAD * 64;
  const ushort* Kp = K + (size_t)bh * kSPAD * 64;
  const ushort* Vp = V + (size_t)bh * kSPAD * 64;

  int tid = threadIdx.x, w = tid >> 6, l = tid & 63;
  int lr = l & 15, lh = l >> 4;
  int q0 = qb * 64 + w * 16;

  s16x8 aq[2];
#pragma unroll
  for (int kk = 0; kk < 2; ++kk)
    aq[kk] = *(const s16x8*)(Qp + (size_t)(q0 + lr) * 64 + kk * 32 + lh * 8);

  f32x4 o[4] = {};
  float mrow[4], lsum[4];
#pragma unroll
  for (int r = 0; r < 4; ++r) { mrow[r] = -1e30f; lsum[r] = 0.0f; }

  const float sc = 0.125f * 1.4426950408889634f;   // (1/sqrt(64)) * log2(e), exp2-based softmax
  int vrp = tid & 15, vcg = tid >> 4;

  for (int t = 0; t < kNT; ++t) {
    int kv0 = t * 32;
    __syncthreads();
    {  // stage K tile with XOR swizzle via pre-swizzled global source (m173 pattern)
      int c = w * 64 + l;
      int srcoff = (c * 16) ^ (((c >> 3) & 7) << 4);
      GLOAD16((const char*)Kp + (size_t)kv0 * 128 + srcoff, (char*)lsK + w * 1024);
    }
    {  // stage V^T: row-pair packed b32 writes (2-way conflicts only)
      const ushort* vb = Vp + (size_t)(kv0 + vrp * 2) * 64 + vcg * 4;
      s16x4 v0 = *(const s16x4*)vb;
      s16x4 v1 = *(const s16x4*)(vb + 64);
#pragma unroll
      for (int j = 0; j < 4; ++j) {
        unsigned pk = (unsigned)(ushort)v0[j] | ((unsigned)(ushort)v1[j] << 16);
        *(unsigned*)&lsVt[(vcg * 4 + j) * 40 + vrp * 2] = pk;
      }
    }
    __syncthreads();

    // scores: [16q x 32k]
    f32x4 s0 = {}, s1 = {};
#pragma unroll
    for (int kk = 0; kk < 2; ++kk) {
      int row0 = lr, row1 = 16 + lr;
      s16x8 b0 = *(const s16x8*)((const char*)lsK + ((row0 * 128 + (kk * 32 + lh * 8) * 2) ^ ((row0 & 7) << 4)));
      s16x8 b1 = *(const s16x8*)((const char*)lsK + ((row1 * 128 + (kk * 32 + lh * 8) * 2) ^ ((row1 & 7) << 4)));
      s0 = mfma16(aq[kk], b0, s0);
      s1 = mfma16(aq[kk], b1, s1);
    }
#pragma unroll
    for (int r = 0; r < 4; ++r) { s0[r] *= sc; s1[r] *= sc; }
    if (t == kNT - 1) {                       // mask tail cols >= 2274
#pragma unroll
      for (int r = 0; r < 4; ++r) {
        s0[r] = (kv0 + lr >= kS) ? -1e30f : s0[r];
        s1[r] = -1e30f;                       // kv0+16+lr >= 2274 always on last tile
      }
    }
    // online softmax (rows live in 16-lane groups)
    float pm[4], al[4], rs[4];
#pragma unroll
    for (int r = 0; r < 4; ++r) pm[r] = fmaxf(s0[r], s1[r]);
#pragma unroll
    for (int m = 1; m < 16; m <<= 1)
#pragma unroll
      for (int r = 0; r < 4; ++r) pm[r] = fmaxf(pm[r], __shfl_xor(pm[r], m));
#pragma unroll
    for (int r = 0; r < 4; ++r) {
      float nm = fmaxf(mrow[r], pm[r]);
      al[r] = exp2f(mrow[r] - nm);
      mrow[r] = nm;
    }
#pragma unroll
    for (int r = 0; r < 4; ++r) {
      s0[r] = exp2f(s0[r] - mrow[r]);
      s1[r] = exp2f(s1[r] - mrow[r]);
      rs[r] = s0[r] + s1[r];
    }
#pragma unroll
    for (int m = 1; m < 16; m <<= 1)
#pragma unroll
      for (int r = 0; r < 4; ++r) rs[r] += __shfl_xor(rs[r], m);
#pragma unroll
    for (int r = 0; r < 4; ++r) lsum[r] = lsum[r] * al[r] + rs[r];
#pragma unroll
    for (int db = 0; db < 4; ++db)
#pragma unroll
      for (int r = 0; r < 4; ++r) o[db][r] *= al[r];
    // P -> LDS (per-wave private; same-wave DS ops drained by lgkmcnt)
#pragma unroll
    for (int r = 0; r < 4; ++r) {
      int prow = lh * 4 + r;
      lsP[w][prow * 40 + lr] = f2bf(s0[r]);
      lsP[w][prow * 40 + 16 + lr] = f2bf(s1[r]);
    }
    asm volatile("s_waitcnt lgkmcnt(0)" ::: "memory");
    __builtin_amdgcn_sched_barrier(0);
    s16x8 pa = *(const s16x8*)&lsP[w][lr * 40 + lh * 8];
#pragma unroll
    for (int db = 0; db < 4; ++db) {
      s16x8 bv = *(const s16x8*)&lsVt[(db * 16 + lr) * 40 + lh * 8];
      o[db] = mfma16(pa, bv, o[db]);
    }
  }

  int b = bh >> 4, h = bh & 15;
#pragma unroll
  for (int db = 0; db < 4; ++db) {
#pragma unroll
    for (int r = 0; r < 4; ++r) {
      int srow = q0 + lh * 4 + r;
      if (srow < kS) {
        float val = o[db][r] / lsum[r];
        AO[(size_t)(b * kS + srow) * kD + h * 64 + db * 16 + lr] = f2bf(val);
      }
    }
  }
}

// ---------------- launch ----------------
extern "C" void kernel_launch(void* const* d_in, const int* in_sizes, int n_in,
                              void* d_out, int out_size, void* d_ws, size_t ws_size,
                              hipStream_t stream) {
  const float* hid  = (const float*)d_in[0];
  const float* enc  = (const float*)d_in[1];
  const float* cosb = (const float*)d_in[2];
  const float* sinb = (const float*)d_in[3];
  const float* wq   = (const float*)d_in[4];
  const float* bq   = (const float*)d_in[5];
  const float* wk   = (const float*)d_in[6];
  const float* bk   = (const float*)d_in[7];
  const float* wv   = (const float*)d_in[8];
  const float* bv   = (const float*)d_in[9];
  const float* wo   = (const float*)d_in[10];
  const float* bo   = (const float*)d_in[11];
  const float* lnqw = (const float*)d_in[12];
  const float* lnqb = (const float*)d_in[13];
  const float* lnkw = (const float*)d_in[14];
  const float* lnkb = (const float*)d_in[15];

  if (ws_size < 112197632u) return;  // need ~107 MB scratch

  char* ws = (char*)d_ws;
  ushort* Xb   = (ushort*)(ws);                  //  9,437,184 B  [4608][1024] bf16
  ushort* Wqkv = (ushort*)(ws + 9437184);        //  6,291,456 B  [3072][1024] bf16
  ushort* Wo   = (ushort*)(ws + 15728640);       //  2,097,152 B  [1024][1024] bf16
  float*  Y    = (float*)(ws + 17825792);        // 56,623,104 B  [4608][3072] f32
  ushort* Qb   = (ushort*)(ws + 74448896);       //  9,437,184 B  [32][2304][64] bf16
  ushort* Kb   = (ushort*)(ws + 83886080);       //  9,437,184 B
  ushort* Vb   = (ushort*)(ws + 93323264);       //  9,437,184 B
  ushort* AO   = (ushort*)(ws + 102760448);      //  9,437,184 B  [4608][1024] bf16

  float* out = (float*)d_out;

  k_prep_w<<<dim3(4096), dim3(256), 0, stream>>>(wq, wk, wv, wo, Wqkv, Wo);
  k_prep_x<<<dim3(4668), dim3(256), 0, stream>>>(hid, enc, Xb, AO);
  k_gemm<0><<<dim3(36 * 24), dim3(256), 0, stream>>>(Xb, Wqkv, Y, (float*)nullptr, (const float*)nullptr, 3072, 1024);
  k_lnrope<<<dim3(18432), dim3(256), 0, stream>>>(Y, bq, bk, bv, lnqw, lnqb, lnkw, lnkb, cosb, sinb, Qb, Kb, Vb);
  k_attn<<<dim3(32 * 36), dim3(256), 0, stream>>>(Qb, Kb, Vb, AO);
  k_gemm<1><<<dim3(36 * 8), dim3(256), 0, stream>>>(AO, Wo, (float*)nullptr, out, bo, 1024, 1024);
}

// Round 7
// 280.332 us; speedup vs baseline: 41.0500x; 1.3477x over previous
//
#include <hip/hip_runtime.h>
#include <hip/hip_bf16.h>

typedef __attribute__((ext_vector_type(4))) float f32x4;
typedef __attribute__((ext_vector_type(8))) short s16x8;
typedef __attribute__((ext_vector_type(4))) short s16x4;

#define GLOAD16(g, s) __builtin_amdgcn_global_load_lds((const __attribute__((address_space(1))) void*)(g), (__attribute__((address_space(3))) void*)(s), 16, 0, 0)

static constexpr int kB    = 2;
static constexpr int kSTXT = 226;
static constexpr int kSVID = 2048;
static constexpr int kD    = 1024;
static constexpr int kS    = kSTXT + kSVID;   // 2274
static constexpr int kBS   = kB * kS;         // 4548
static constexpr int kMPAD = 4608;            // 36*128
static constexpr int kSPAD = 2304;            // 36*64
static constexpr int kNT64 = kSPAD / 64;      // 36

static __device__ __forceinline__ ushort f2bf(float f) {
  unsigned u = __float_as_uint(f);
  u += 0x7fffu + ((u >> 16) & 1u);            // RNE (finite data only)
  return (ushort)(u >> 16);
}

static __device__ __forceinline__ f32x4 mfma16(s16x8 a, s16x8 b, f32x4 c) {
  return __builtin_amdgcn_mfma_f32_16x16x32_bf16(a, b, c, 0, 0, 0);
}

// ---------------- prep: weights -> bf16 ----------------
__global__ __launch_bounds__(256) void k_prep_w(const float* __restrict__ wq, const float* __restrict__ wk,
                                                const float* __restrict__ wv, const float* __restrict__ wo,
                                                ushort* __restrict__ Wqkv, ushort* __restrict__ Wo) {
  int q = blockIdx.x * 256 + threadIdx.x;
  int reg = q >> 18;
  int off = (q & 262143) << 2;
  const float* sp = (reg == 0) ? wq : (reg == 1) ? wk : (reg == 2) ? wv : wo;
  float4 v = *(const float4*)(sp + off);
  ushort4 o;
  o.x = f2bf(v.x); o.y = f2bf(v.y); o.z = f2bf(v.z); o.w = f2bf(v.w);
  ushort* dst = (reg < 3) ? (Wqkv + ((size_t)reg << 20) + off) : (Wo + off);
  *(ushort4*)dst = o;
}

// ---------------- prep: X concat+cast, zero AO pad rows ----------------
__global__ __launch_bounds__(256) void k_prep_x(const float* __restrict__ hid, const float* __restrict__ enc,
                                                ushort* __restrict__ Xb, ushort* __restrict__ AO) {
  int q = blockIdx.x * 256 + threadIdx.x;
  const int XQ = (kMPAD * kD) / 4;
  if (q < XQ) {
    int row = q >> 8;
    int cq = (q & 255) << 2;
    ushort4 o;
    if (row < kBS) {
      int b = row / kS, s = row - b * kS;
      const float* src = (s < kSTXT) ? (enc + (size_t)(b * kSTXT + s) * kD + cq)
                                     : (hid + (size_t)(b * kSVID + (s - kSTXT)) * kD + cq);
      float4 v = *(const float4*)src;
      o.x = f2bf(v.x); o.y = f2bf(v.y); o.z = f2bf(v.z); o.w = f2bf(v.w);
    } else {
      o.x = 0; o.y = 0; o.z = 0; o.w = 0;
    }
    *(ushort4*)(Xb + (size_t)row * kD + cq) = o;
  } else {
    int p = q - XQ;
    ushort4 z; z.x = 0; z.y = 0; z.z = 0; z.w = 0;
    *(ushort4*)(AO + (size_t)kBS * kD + (size_t)p * 4) = z;
  }
}

// ---------------- bf16 GEMM, C = A * B^T ----------------
template<int EPI>
__global__ __launch_bounds__(256) void k_gemm(const ushort* __restrict__ A, const ushort* __restrict__ Bm,
                                              float* __restrict__ C, float* __restrict__ OutF,
                                              const float* __restrict__ bias, int N, int K) {
  __shared__ ushort lsA[4096];
  __shared__ ushort lsB[4096];
  int nt = N >> 7;
  int mt = blockIdx.x / nt, ntl = blockIdx.x - mt * nt;
  int m0 = mt << 7, n0 = ntl << 7;
  int tid = threadIdx.x;
  int w = tid >> 6, l = tid & 63;
  int wm = (w >> 1) << 6, wn = (w & 1) << 6;
  int lr = l & 15, lh = l >> 4;

  f32x4 acc[4][4] = {};

  for (int k0 = 0; k0 < K; k0 += 32) {
    __syncthreads();
#pragma unroll
    for (int i = 0; i < 2; ++i) {
      int c = i * 256 + w * 64 + l;
      GLOAD16(A + (size_t)(m0 + (c >> 2)) * K + k0 + ((c & 3) << 3),
              lsA + ((size_t)(i * 256 + w * 64) << 3));
      GLOAD16(Bm + (size_t)(n0 + (c >> 2)) * K + k0 + ((c & 3) << 3),
              lsB + ((size_t)(i * 256 + w * 64) << 3));
    }
    __syncthreads();
    s16x8 af[4], bfr[4];
#pragma unroll
    for (int mi = 0; mi < 4; ++mi) af[mi] = *(const s16x8*)&lsA[(wm + mi * 16 + lr) * 32 + lh * 8];
#pragma unroll
    for (int ni = 0; ni < 4; ++ni) bfr[ni] = *(const s16x8*)&lsB[(wn + ni * 16 + lr) * 32 + lh * 8];
#pragma unroll
    for (int mi = 0; mi < 4; ++mi)
#pragma unroll
      for (int ni = 0; ni < 4; ++ni)
        acc[mi][ni] = mfma16(af[mi], bfr[ni], acc[mi][ni]);
  }

#pragma unroll
  for (int mi = 0; mi < 4; ++mi) {
#pragma unroll
    for (int ni = 0; ni < 4; ++ni) {
#pragma unroll
      for (int r = 0; r < 4; ++r) {
        int row = m0 + wm + mi * 16 + lh * 4 + r;
        int col = n0 + wn + ni * 16 + lr;
        if (EPI == 0) {
          C[(size_t)row * N + col] = acc[mi][ni][r];
        } else {
          if (row < kBS) {
            float v = acc[mi][ni][r] + bias[col];
            int b = row / kS, s = row - b * kS;
            size_t o = (s >= kSTXT) ? ((size_t)(b * kSVID + s - kSTXT) * kD + col)
                                    : ((size_t)kB * kSVID * kD + (size_t)(b * kSTXT + s) * kD + col);
            OutF[o] = v;
          }
        }
      }
    }
  }
}

// ---------------- bias + per-head LN + RoPE -> Q/K/V bf16 panels [BH][SPAD][64] ----------------
// Q is pre-scaled by (1/sqrt(64))*log2(e) so the attention kernel does exp2(S - m) directly.
__global__ __launch_bounds__(256) void k_lnrope(const float* __restrict__ Y,
    const float* __restrict__ bq, const float* __restrict__ bk, const float* __restrict__ bv,
    const float* __restrict__ lnqw, const float* __restrict__ lnqb,
    const float* __restrict__ lnkw, const float* __restrict__ lnkb,
    const float* __restrict__ cosb, const float* __restrict__ sinb,
    ushort* __restrict__ Qo, ushort* __restrict__ Ko, ushort* __restrict__ Vo) {
  const float kQS = 0.125f * 1.4426950408889634f;
  int wid = (blockIdx.x * 256 + threadIdx.x) >> 6;
  int l = threadIdx.x & 63;
  int bh = wid / kSPAD;
  int s = wid - bh * kSPAD;
  size_t po = (size_t)wid * 64 + l;
  if (s >= kS) { Qo[po] = 0; Ko[po] = 0; Vo[po] = 0; return; }
  int b = bh >> 4, h = bh & 15;
  int row = b * kS + s;
  int col = h * 64 + l;
  const float* yr = Y + (size_t)row * 3072;
  float q = yr[col] + bq[col];
  float k = yr[1024 + col] + bk[col];
  float v = yr[2048 + col] + bv[col];
  float sq = q, sk = k;
#pragma unroll
  for (int m = 1; m < 64; m <<= 1) { sq += __shfl_xor(sq, m); sk += __shfl_xor(sk, m); }
  float dq = q - sq * (1.0f / 64.0f);
  float dk = k - sk * (1.0f / 64.0f);
  float vq = dq * dq, vk = dk * dk;
#pragma unroll
  for (int m = 1; m < 64; m <<= 1) { vq += __shfl_xor(vq, m); vk += __shfl_xor(vk, m); }
  q = dq * rsqrtf(vq * (1.0f / 64.0f) + 1e-5f) * lnqw[l] + lnqb[l];
  k = dk * rsqrtf(vk * (1.0f / 64.0f) + 1e-5f) * lnkw[l] + lnkb[l];
  if (s >= kSTXT) {
    int pos = s - kSTXT;
    float c = cosb[pos * 64 + l], sn = sinb[pos * 64 + l];
    float qp = __shfl_xor(q, 1), kp = __shfl_xor(k, 1);
    float sg = (l & 1) ? 1.0f : -1.0f;
    q = q * c + sg * qp * sn;
    k = k * c + sg * kp * sn;
  }
  Qo[po] = f2bf(q * kQS); Ko[po] = f2bf(k); Vo[po] = f2bf(v);
}

// ---------------- flash attention (swapped operands, KVBLK=64, defer-max) ----------------
// grid 1152 blocks, 4 waves; wave = 16 q rows (lane owns q = lane&15); KV tile = 64 rows.
__global__ __launch_bounds__(256) void k_attn(const ushort* __restrict__ Q, const ushort* __restrict__ K,
                                              const ushort* __restrict__ V, ushort* __restrict__ AO) {
  __shared__ ushort lsK[64 * 64];          // XOR-swizzled rows (128B), 8KB
  __shared__ ushort lsVt[2][64][40];       // V^T per 32-k half: [d][k_local], stride 40
  __shared__ ushort lsP[4][2][16][40];     // per-wave P[q][k_local] per half, stride 40

  int bid = blockIdx.x;
  int wg = (bid & 7) * 144 + (bid >> 3);   // XCD swizzle (1152 % 8 == 0 -> bijective)
  int bh = wg / 36, qb = wg - bh * 36;
  const ushort* Qp = Q + (size_t)bh * kSPAD * 64;
  const ushort* Kp = K + (size_t)bh * kSPAD * 64;
  const ushort* Vp = V + (size_t)bh * kSPAD * 64;

  int tid = threadIdx.x, w = tid >> 6, l = tid & 63;
  int lr = l & 15, lh = l >> 4;
  int q0 = qb * 64 + w * 16;

  s16x8 aq[2];                             // Q fragment (B-side): row q=lr, k=kk*32+lh*8
#pragma unroll
  for (int kk = 0; kk < 2; ++kk)
    aq[kk] = *(const s16x8*)(Qp + (size_t)(q0 + lr) * 64 + kk * 32 + lh * 8);

  f32x4 o[4] = {};                         // O^T frags: o[db][r] = O[d=db*16+lh*4+r][q=lr]
  float m = -1e30f, lsum = 0.0f;           // scalar per-lane (q = lr)

  // staging precomputes
  int c0 = w * 64 + l;
  int src0 = (c0 * 16) ^ (((c0 >> 3) & 7) << 4);
  int c1s = ((c0 + 256) * 16) ^ ((((c0 + 256) >> 3) & 7) << 4);
  const char* kbase = (const char*)Kp;
  char* dst0 = (char*)lsK + (size_t)(w * 64) * 16;
  char* dst1 = (char*)lsK + (size_t)(256 + w * 64) * 16;
  int vrp = tid & 15, vcg = tid >> 4;
  const ushort* vbase = Vp + (size_t)(vrp * 2) * 64 + vcg * 4;

  for (int t = 0; t < kNT64; ++t) {
    __syncthreads();
    GLOAD16(kbase + src0, dst0);           // K tile, pre-swizzled source (m173)
    GLOAD16(kbase + c1s, dst1);
#pragma unroll
    for (int half = 0; half < 2; ++half) { // V^T staging, packed b32 (2-way banks)
      const ushort* vb = vbase + half * 32 * 64;
      s16x4 v0 = *(const s16x4*)vb;
      s16x4 v1 = *(const s16x4*)(vb + 64);
#pragma unroll
      for (int j = 0; j < 4; ++j) {
        unsigned pk = (unsigned)(ushort)v0[j] | ((unsigned)(ushort)v1[j] << 16);
        *(unsigned*)&lsVt[half][vcg * 4 + j][vrp * 2] = pk;
      }
    }
    __syncthreads();

    // QK^T swapped: s[kb] = K-rows(kb*16..+15) x Q -> S^T[k][q=lr]
    f32x4 s[4] = {};
    __builtin_amdgcn_s_setprio(1);
#pragma unroll
    for (int kk = 0; kk < 2; ++kk) {
#pragma unroll
      for (int kb = 0; kb < 4; ++kb) {
        int row = kb * 16 + lr;
        s16x8 bk8 = *(const s16x8*)((const char*)lsK +
                      ((row * 128 + (kk * 32 + lh * 8) * 2) ^ ((lr & 7) << 4)));
        s[kb] = mfma16(bk8, aq[kk], s[kb]);
      }
    }
    __builtin_amdgcn_s_setprio(0);

    if (t == kNT64 - 1) {                  // mask tail k >= kS
      int kv0 = t * 64;
#pragma unroll
      for (int kb = 0; kb < 4; ++kb)
#pragma unroll
        for (int r = 0; r < 4; ++r)
          if (kv0 + kb * 16 + lh * 4 + r >= kS) s[kb][r] = -1e30f;
    }

    // softmax: local 16-max + 2 shfls; defer-max (THR=8 in log2 domain, P <= 256)
    float pm = s[0][0];
#pragma unroll
    for (int kb = 0; kb < 4; ++kb)
#pragma unroll
      for (int r = 0; r < 4; ++r) pm = fmaxf(pm, s[kb][r]);
    pm = fmaxf(pm, __shfl_xor(pm, 16));
    pm = fmaxf(pm, __shfl_xor(pm, 32));
    if (!__all(pm <= m + 8.0f)) {
      float nm = fmaxf(m, pm);
      float al = exp2f(m - nm);
      m = nm;
      lsum *= al;
#pragma unroll
      for (int db = 0; db < 4; ++db)
#pragma unroll
        for (int r = 0; r < 4; ++r) o[db][r] *= al;
    }
    float rs = 0.0f;
#pragma unroll
    for (int kb = 0; kb < 4; ++kb)
#pragma unroll
      for (int r = 0; r < 4; ++r) { s[kb][r] = exp2f(s[kb][r] - m); rs += s[kb][r]; }
    rs += __shfl_xor(rs, 16);
    rs += __shfl_xor(rs, 32);
    lsum += rs;

    // P[q=lr][k] -> lsP (pair-packed b32 writes)
#pragma unroll
    for (int kb = 0; kb < 4; ++kb) {
      unsigned p01 = (unsigned)f2bf(s[kb][0]) | ((unsigned)f2bf(s[kb][1]) << 16);
      unsigned p23 = (unsigned)f2bf(s[kb][2]) | ((unsigned)f2bf(s[kb][3]) << 16);
      int half = kb >> 1, kloc = (kb & 1) * 16 + lh * 4;
      *(unsigned*)&lsP[w][half][lr][kloc] = p01;
      *(unsigned*)&lsP[w][half][lr][kloc + 2] = p23;
    }
    asm volatile("s_waitcnt lgkmcnt(0)" ::: "memory");
    __builtin_amdgcn_sched_barrier(0);

    // PV swapped: o[db] += V^T x P^T  (same LDS read patterns as before)
    __builtin_amdgcn_s_setprio(1);
#pragma unroll
    for (int half = 0; half < 2; ++half) {
      s16x8 pa = *(const s16x8*)&lsP[w][half][lr][lh * 8];
#pragma unroll
      for (int db = 0; db < 4; ++db) {
        s16x8 bv = *(const s16x8*)&lsVt[half][db * 16 + lr][lh * 8];
        o[db] = mfma16(bv, pa, o[db]);
      }
    }
    __builtin_amdgcn_s_setprio(0);

    kbase += 64 * 128;                     // advance one KV tile
    vbase += 64 * 64;
  }

  int b = bh >> 4, h = bh & 15;
  int srow = q0 + lr;
  if (srow < kS) {
    float inv = 1.0f / lsum;
    size_t base = (size_t)(b * kS + srow) * kD + h * 64;
#pragma unroll
    for (int db = 0; db < 4; ++db)
#pragma unroll
      for (int r = 0; r < 4; ++r)
        AO[base + db * 16 + lh * 4 + r] = f2bf(o[db][r] * inv);
  }
}

// ---------------- launch ----------------
extern "C" void kernel_launch(void* const* d_in, const int* in_sizes, int n_in,
                              void* d_out, int out_size, void* d_ws, size_t ws_size,
                              hipStream_t stream) {
  const float* hid  = (const float*)d_in[0];
  const float* enc  = (const float*)d_in[1];
  const float* cosb = (const float*)d_in[2];
  const float* sinb = (const float*)d_in[3];
  const float* wq   = (const float*)d_in[4];
  const float* bq   = (const float*)d_in[5];
  const float* wk   = (const float*)d_in[6];
  const float* bk   = (const float*)d_in[7];
  const float* wv   = (const float*)d_in[8];
  const float* bv   = (const float*)d_in[9];
  const float* wo   = (const float*)d_in[10];
  const float* bo   = (const float*)d_in[11];
  const float* lnqw = (const float*)d_in[12];
  const float* lnqb = (const float*)d_in[13];
  const float* lnkw = (const float*)d_in[14];
  const float* lnkb = (const float*)d_in[15];

  if (ws_size < 112197632u) return;

  char* ws = (char*)d_ws;
  ushort* Xb   = (ushort*)(ws);
  ushort* Wqkv = (ushort*)(ws + 9437184);
  ushort* Wo   = (ushort*)(ws + 15728640);
  float*  Y    = (float*)(ws + 17825792);
  ushort* Qb   = (ushort*)(ws + 74448896);
  ushort* Kb   = (ushort*)(ws + 83886080);
  ushort* Vb   = (ushort*)(ws + 93323264);
  ushort* AO   = (ushort*)(ws + 102760448);

  float* out = (float*)d_out;

  k_prep_w<<<dim3(4096), dim3(256), 0, stream>>>(wq, wk, wv, wo, Wqkv, Wo);
  k_prep_x<<<dim3(4668), dim3(256), 0, stream>>>(hid, enc, Xb, AO);
  k_gemm<0><<<dim3(36 * 24), dim3(256), 0, stream>>>(Xb, Wqkv, Y, (float*)nullptr, (const float*)nullptr, 3072, 1024);
  k_lnrope<<<dim3(18432), dim3(256), 0, stream>>>(Y, bq, bk, bv, lnqw, lnqb, lnkw, lnkb, cosb, sinb, Qb, Kb, Vb);
  k_attn<<<dim3(32 * 36), dim3(256), 0, stream>>>(Qb, Kb, Vb, AO);
  k_gemm<1><<<dim3(36 * 8), dim3(256), 0, stream>>>(AO, Wo, (float*)nullptr, out, bo, 1024, 1024);
}

// Round 8
// 248.681 us; speedup vs baseline: 46.2748x; 1.1273x over previous
//
#include <hip/hip_runtime.h>
#include <hip/hip_bf16.h>

typedef __attribute__((ext_vector_type(4))) float f32x4;
typedef __attribute__((ext_vector_type(8))) short s16x8;
typedef __attribute__((ext_vector_type(4))) short s16x4;

#define GLOAD16(g, s) __builtin_amdgcn_global_load_lds((const __attribute__((address_space(1))) void*)(g), (__attribute__((address_space(3))) void*)(s), 16, 0, 0)

static constexpr int kB    = 2;
static constexpr int kSTXT = 226;
static constexpr int kSVID = 2048;
static constexpr int kD    = 1024;
static constexpr int kS    = kSTXT + kSVID;   // 2274
static constexpr int kBS   = kB * kS;         // 4548
static constexpr int kMPAD = 4608;            // 36*128
static constexpr int kSPAD = 2304;            // 36*64
static constexpr int kNT64 = kSPAD / 64;      // 36

static __device__ __forceinline__ ushort f2bf(float f) {
  unsigned u = __float_as_uint(f);
  u += 0x7fffu + ((u >> 16) & 1u);            // RNE (finite data only)
  return (ushort)(u >> 16);
}

static __device__ __forceinline__ f32x4 mfma16(s16x8 a, s16x8 b, f32x4 c) {
  return __builtin_amdgcn_mfma_f32_16x16x32_bf16(a, b, c, 0, 0, 0);
}

// ---------------- prep: weights -> bf16 ----------------
__global__ __launch_bounds__(256) void k_prep_w(const float* __restrict__ wq, const float* __restrict__ wk,
                                                const float* __restrict__ wv, const float* __restrict__ wo,
                                                ushort* __restrict__ Wqkv, ushort* __restrict__ Wo) {
  int q = blockIdx.x * 256 + threadIdx.x;
  int reg = q >> 18;
  int off = (q & 262143) << 2;
  const float* sp = (reg == 0) ? wq : (reg == 1) ? wk : (reg == 2) ? wv : wo;
  float4 v = *(const float4*)(sp + off);
  ushort4 o;
  o.x = f2bf(v.x); o.y = f2bf(v.y); o.z = f2bf(v.z); o.w = f2bf(v.w);
  ushort* dst = (reg < 3) ? (Wqkv + ((size_t)reg << 20) + off) : (Wo + off);
  *(ushort4*)dst = o;
}

// ---------------- prep: X concat+cast, zero AO pad rows ----------------
__global__ __launch_bounds__(256) void k_prep_x(const float* __restrict__ hid, const float* __restrict__ enc,
                                                ushort* __restrict__ Xb, ushort* __restrict__ AO) {
  int q = blockIdx.x * 256 + threadIdx.x;
  const int XQ = (kMPAD * kD) / 4;
  if (q < XQ) {
    int row = q >> 8;
    int cq = (q & 255) << 2;
    ushort4 o;
    if (row < kBS) {
      int b = row / kS, s = row - b * kS;
      const float* src = (s < kSTXT) ? (enc + (size_t)(b * kSTXT + s) * kD + cq)
                                     : (hid + (size_t)(b * kSVID + (s - kSTXT)) * kD + cq);
      float4 v = *(const float4*)src;
      o.x = f2bf(v.x); o.y = f2bf(v.y); o.z = f2bf(v.z); o.w = f2bf(v.w);
    } else {
      o.x = 0; o.y = 0; o.z = 0; o.w = 0;
    }
    *(ushort4*)(Xb + (size_t)row * kD + cq) = o;
  } else {
    int p = q - XQ;
    ushort4 z; z.x = 0; z.y = 0; z.z = 0; z.w = 0;
    *(ushort4*)(AO + (size_t)kBS * kD + (size_t)p * 4) = z;
  }
}

// ---------------- bf16 GEMM, C = A * B^T ----------------
template<int EPI>
__global__ __launch_bounds__(256) void k_gemm(const ushort* __restrict__ A, const ushort* __restrict__ Bm,
                                              float* __restrict__ C, float* __restrict__ OutF,
                                              const float* __restrict__ bias, int N, int K) {
  __shared__ ushort lsA[4096];
  __shared__ ushort lsB[4096];
  int nt = N >> 7;
  int mt = blockIdx.x / nt, ntl = blockIdx.x - mt * nt;
  int m0 = mt << 7, n0 = ntl << 7;
  int tid = threadIdx.x;
  int w = tid >> 6, l = tid & 63;
  int wm = (w >> 1) << 6, wn = (w & 1) << 6;
  int lr = l & 15, lh = l >> 4;

  f32x4 acc[4][4] = {};

  for (int k0 = 0; k0 < K; k0 += 32) {
    __syncthreads();
#pragma unroll
    for (int i = 0; i < 2; ++i) {
      int c = i * 256 + w * 64 + l;
      GLOAD16(A + (size_t)(m0 + (c >> 2)) * K + k0 + ((c & 3) << 3),
              lsA + ((size_t)(i * 256 + w * 64) << 3));
      GLOAD16(Bm + (size_t)(n0 + (c >> 2)) * K + k0 + ((c & 3) << 3),
              lsB + ((size_t)(i * 256 + w * 64) << 3));
    }
    __syncthreads();
    s16x8 af[4], bfr[4];
#pragma unroll
    for (int mi = 0; mi < 4; ++mi) af[mi] = *(const s16x8*)&lsA[(wm + mi * 16 + lr) * 32 + lh * 8];
#pragma unroll
    for (int ni = 0; ni < 4; ++ni) bfr[ni] = *(const s16x8*)&lsB[(wn + ni * 16 + lr) * 32 + lh * 8];
#pragma unroll
    for (int mi = 0; mi < 4; ++mi)
#pragma unroll
      for (int ni = 0; ni < 4; ++ni)
        acc[mi][ni] = mfma16(af[mi], bfr[ni], acc[mi][ni]);
  }

#pragma unroll
  for (int mi = 0; mi < 4; ++mi) {
#pragma unroll
    for (int ni = 0; ni < 4; ++ni) {
#pragma unroll
      for (int r = 0; r < 4; ++r) {
        int row = m0 + wm + mi * 16 + lh * 4 + r;
        int col = n0 + wn + ni * 16 + lr;
        if (EPI == 0) {
          C[(size_t)row * N + col] = acc[mi][ni][r];
        } else {
          if (row < kBS) {
            float v = acc[mi][ni][r] + bias[col];
            int b = row / kS, s = row - b * kS;
            size_t o = (s >= kSTXT) ? ((size_t)(b * kSVID + s - kSTXT) * kD + col)
                                    : ((size_t)kB * kSVID * kD + (size_t)(b * kSTXT + s) * kD + col);
            OutF[o] = v;
          }
        }
      }
    }
  }
}

// ---------------- bias + per-head LN + RoPE -> Q/K/V bf16 panels [BH][SPAD][64] ----------------
// Q pre-scaled by (1/sqrt(64))*log2(e).
__global__ __launch_bounds__(256) void k_lnrope(const float* __restrict__ Y,
    const float* __restrict__ bq, const float* __restrict__ bk, const float* __restrict__ bv,
    const float* __restrict__ lnqw, const float* __restrict__ lnqb,
    const float* __restrict__ lnkw, const float* __restrict__ lnkb,
    const float* __restrict__ cosb, const float* __restrict__ sinb,
    ushort* __restrict__ Qo, ushort* __restrict__ Ko, ushort* __restrict__ Vo) {
  const float kQS = 0.125f * 1.4426950408889634f;
  int wid = (blockIdx.x * 256 + threadIdx.x) >> 6;
  int l = threadIdx.x & 63;
  int bh = wid / kSPAD;
  int s = wid - bh * kSPAD;
  size_t po = (size_t)wid * 64 + l;
  if (s >= kS) { Qo[po] = 0; Ko[po] = 0; Vo[po] = 0; return; }
  int b = bh >> 4, h = bh & 15;
  int row = b * kS + s;
  int col = h * 64 + l;
  const float* yr = Y + (size_t)row * 3072;
  float q = yr[col] + bq[col];
  float k = yr[1024 + col] + bk[col];
  float v = yr[2048 + col] + bv[col];
  float sq = q, sk = k;
#pragma unroll
  for (int m = 1; m < 64; m <<= 1) { sq += __shfl_xor(sq, m); sk += __shfl_xor(sk, m); }
  float dq = q - sq * (1.0f / 64.0f);
  float dk = k - sk * (1.0f / 64.0f);
  float vq = dq * dq, vk = dk * dk;
#pragma unroll
  for (int m = 1; m < 64; m <<= 1) { vq += __shfl_xor(vq, m); vk += __shfl_xor(vk, m); }
  q = dq * rsqrtf(vq * (1.0f / 64.0f) + 1e-5f) * lnqw[l] + lnqb[l];
  k = dk * rsqrtf(vk * (1.0f / 64.0f) + 1e-5f) * lnkw[l] + lnkb[l];
  if (s >= kSTXT) {
    int pos = s - kSTXT;
    float c = cosb[pos * 64 + l], sn = sinb[pos * 64 + l];
    float qp = __shfl_xor(q, 1), kp = __shfl_xor(k, 1);
    float sg = (l & 1) ? 1.0f : -1.0f;
    q = q * c + sg * qp * sn;
    k = k * c + sg * kp * sn;
  }
  Qo[po] = f2bf(q * kQS); Ko[po] = f2bf(k); Vo[po] = f2bf(v);
}

// ---------------- V transpose: Vb [bh][kSPAD][64] -> Vt [bh][64][kSPAD] ----------------
__global__ __launch_bounds__(256) void k_vt(const ushort* __restrict__ Vb, ushort* __restrict__ Vt) {
  __shared__ ushort lsT[64 * 68];                 // row stride 68 (8B-aligned, 2-way-free reads)
  int bid = blockIdx.x;                           // 32 bh * 36 s-blocks
  int bh = bid / 36, sb = bid - bh * 36;
  int s0 = sb * 64;
  const ushort* src = Vb + (size_t)bh * kSPAD * 64 + (size_t)s0 * 64;
  ushort* dst = Vt + (size_t)bh * 64 * kSPAD;
  int t = threadIdx.x;
#pragma unroll
  for (int i = 0; i < 4; ++i) {                   // stage 64x64 tile (8B chunks)
    int q = i * 256 + t;
    int row = q >> 4, c4 = (q & 15) * 4;
    *(s16x4*)&lsT[row * 68 + c4] = *(const s16x4*)(src + (size_t)row * 64 + c4);
  }
  __syncthreads();
  int l = t & 63, wv = t >> 6;
#pragma unroll
  for (int c = 0; c < 16; ++c) {                  // coalesced transposed writes (128B/instr)
    int d = wv * 16 + c;
    dst[(size_t)d * kSPAD + s0 + l] = lsT[l * 68 + d];
  }
}

// ---------------- flash attention (swapped operands, KVBLK=64, dbuf DMA staging) ----------------
// grid 1152 blocks, 4 waves; wave = 16 q rows (lane owns q = lane&15); KV tile = 64.
__global__ __launch_bounds__(256) void k_attn(const ushort* __restrict__ Q, const ushort* __restrict__ K,
                                              const ushort* __restrict__ Vt, ushort* __restrict__ AO) {
  __shared__ ushort lsK[2][4096];          // [64 kv][64 d] XOR-swizzled, 8KB each
  __shared__ ushort lsVt[2][4096];         // [64 d][64 kv] XOR-swizzled, 8KB each
  __shared__ ushort lsP[4][2][16][40];     // per-wave P[q][k_local] per 32-half

  int bid = blockIdx.x;
  int wg = (bid & 7) * 144 + (bid >> 3);   // XCD swizzle (1152 % 8 == 0 -> bijective)
  int bh = wg / 36, qb = wg - bh * 36;
  const ushort* Qp = Q + (size_t)bh * kSPAD * 64;
  const char* Kg = (const char*)(K + (size_t)bh * kSPAD * 64);
  const char* Vg = (const char*)(Vt + (size_t)bh * 64 * kSPAD);

  int tid = threadIdx.x, w = tid >> 6, l = tid & 63;
  int lr = l & 15, lh = l >> 4;
  int q0 = qb * 64 + w * 16;

  s16x8 aq[2];                             // Q fragment (B-side): row q=lr, k=kk*32+lh*8
#pragma unroll
  for (int kk = 0; kk < 2; ++kk)
    aq[kk] = *(const s16x8*)(Qp + (size_t)(q0 + lr) * 64 + kk * 32 + lh * 8);

  f32x4 o[4] = {};                         // O^T frags: o[db][r] = O[d=db*16+lh*4+r][q=lr]
  float m = -1e30f, lsum = 0.0f;

  // staging precomputes: chunks c0, c1 (16B each); row = c>>3, col = (c&7)*16
  int c0 = w * 64 + l, c1 = c0 + 256;
  int kr0 = c0 >> 3, kr1 = c1 >> 3;
  int ksrc0 = (c0 * 16) ^ ((kr0 & 7) << 4);               // K rows contiguous (128B)
  int ksrc1 = (c1 * 16) ^ ((kr1 & 7) << 4);
  int vsrc0 = kr0 * (kSPAD * 2) + (((c0 & 7) * 16) ^ ((kr0 & 7) << 4));  // V^T row stride 4608B
  int vsrc1 = kr1 * (kSPAD * 2) + (((c1 & 7) * 16) ^ ((kr1 & 7) << 4));

#define ISSUE_TILE(buf, t) do {                                              \
    GLOAD16(Kg + (size_t)(t) * 8192 + ksrc0, (char*)lsK[buf] + c0 * 16);     \
    GLOAD16(Kg + (size_t)(t) * 8192 + ksrc1, (char*)lsK[buf] + c1 * 16);     \
    GLOAD16(Vg + (size_t)(t) * 128 + vsrc0,  (char*)lsVt[buf] + c0 * 16);    \
    GLOAD16(Vg + (size_t)(t) * 128 + vsrc1,  (char*)lsVt[buf] + c1 * 16);    \
  } while (0)

  ISSUE_TILE(0, 0);                        // prologue

  for (int t = 0; t < kNT64; ++t) {
    int cur = t & 1;
    __builtin_amdgcn_s_barrier();          // all waves done reading buf[cur^1]
    if (t + 1 < kNT64) {
      ISSUE_TILE(cur ^ 1, t + 1);          // prefetch next tile (4 DMAs in flight)
      asm volatile("s_waitcnt vmcnt(4)" ::: "memory");   // tile t's 4 DMAs done
    } else {
      asm volatile("s_waitcnt vmcnt(0)" ::: "memory");
    }
    __builtin_amdgcn_s_barrier();
    __builtin_amdgcn_sched_barrier(0);

    // QK^T swapped: s[kb] = K-rows x Q -> S^T[k][q=lr]
    f32x4 s[4] = {};
    __builtin_amdgcn_s_setprio(1);
#pragma unroll
    for (int kk = 0; kk < 2; ++kk) {
#pragma unroll
      for (int kb = 0; kb < 4; ++kb) {
        int row = kb * 16 + lr;
        s16x8 bk8 = *(const s16x8*)((const char*)lsK[cur] +
                      ((row * 128 + kk * 64 + lh * 16) ^ ((lr & 7) << 4)));
        s[kb] = mfma16(bk8, aq[kk], s[kb]);
      }
    }
    __builtin_amdgcn_s_setprio(0);

    if (t == kNT64 - 1) {                  // mask tail k >= kS
      int kv0 = t * 64;
#pragma unroll
      for (int kb = 0; kb < 4; ++kb)
#pragma unroll
        for (int r = 0; r < 4; ++r)
          if (kv0 + kb * 16 + lh * 4 + r >= kS) s[kb][r] = -1e30f;
    }

    // softmax: local 16-max + 2 shfls; defer-max (THR=8 in exp2 domain)
    float pm = s[0][0];
#pragma unroll
    for (int kb = 0; kb < 4; ++kb)
#pragma unroll
      for (int r = 0; r < 4; ++r) pm = fmaxf(pm, s[kb][r]);
    pm = fmaxf(pm, __shfl_xor(pm, 16));
    pm = fmaxf(pm, __shfl_xor(pm, 32));
    if (!__all(pm <= m + 8.0f)) {
      float nm = fmaxf(m, pm);
      float al = exp2f(m - nm);
      m = nm;
      lsum *= al;
#pragma unroll
      for (int db = 0; db < 4; ++db)
#pragma unroll
        for (int r = 0; r < 4; ++r) o[db][r] *= al;
    }
    float rs = 0.0f;
#pragma unroll
    for (int kb = 0; kb < 4; ++kb)
#pragma unroll
      for (int r = 0; r < 4; ++r) { s[kb][r] = exp2f(s[kb][r] - m); rs += s[kb][r]; }
    rs += __shfl_xor(rs, 16);
    rs += __shfl_xor(rs, 32);
    lsum += rs;

    // P[q=lr][k] -> lsP (pair-packed b32 writes, wave-private)
#pragma unroll
    for (int kb = 0; kb < 4; ++kb) {
      unsigned p01 = (unsigned)f2bf(s[kb][0]) | ((unsigned)f2bf(s[kb][1]) << 16);
      unsigned p23 = (unsigned)f2bf(s[kb][2]) | ((unsigned)f2bf(s[kb][3]) << 16);
      int half = kb >> 1, kloc = (kb & 1) * 16 + lh * 4;
      *(unsigned*)&lsP[w][half][lr][kloc] = p01;
      *(unsigned*)&lsP[w][half][lr][kloc + 2] = p23;
    }
    asm volatile("s_waitcnt lgkmcnt(0)" ::: "memory");
    __builtin_amdgcn_sched_barrier(0);

    // PV swapped: o[db] += V^T x P^T
    __builtin_amdgcn_s_setprio(1);
#pragma unroll
    for (int half = 0; half < 2; ++half) {
      s16x8 pa = *(const s16x8*)&lsP[w][half][lr][lh * 8];
#pragma unroll
      for (int db = 0; db < 4; ++db) {
        int d = db * 16 + lr;
        s16x8 bv = *(const s16x8*)((const char*)lsVt[cur] +
                     ((d * 128 + half * 64 + lh * 16) ^ ((lr & 7) << 4)));
        o[db] = mfma16(bv, pa, o[db]);
      }
    }
    __builtin_amdgcn_s_setprio(0);
  }
#undef ISSUE_TILE

  int b = bh >> 4, h = bh & 15;
  int srow = q0 + lr;
  if (srow < kS) {
    float inv = 1.0f / lsum;
    size_t base = (size_t)(b * kS + srow) * kD + h * 64;
#pragma unroll
    for (int db = 0; db < 4; ++db)
#pragma unroll
      for (int r = 0; r < 4; ++r)
        AO[base + db * 16 + lh * 4 + r] = f2bf(o[db][r] * inv);
  }
}

// ---------------- launch ----------------
extern "C" void kernel_launch(void* const* d_in, const int* in_sizes, int n_in,
                              void* d_out, int out_size, void* d_ws, size_t ws_size,
                              hipStream_t stream) {
  const float* hid  = (const float*)d_in[0];
  const float* enc  = (const float*)d_in[1];
  const float* cosb = (const float*)d_in[2];
  const float* sinb = (const float*)d_in[3];
  const float* wq   = (const float*)d_in[4];
  const float* bq   = (const float*)d_in[5];
  const float* wk   = (const float*)d_in[6];
  const float* bk   = (const float*)d_in[7];
  const float* wv   = (const float*)d_in[8];
  const float* bv   = (const float*)d_in[9];
  const float* wo   = (const float*)d_in[10];
  const float* bo   = (const float*)d_in[11];
  const float* lnqw = (const float*)d_in[12];
  const float* lnqb = (const float*)d_in[13];
  const float* lnkw = (const float*)d_in[14];
  const float* lnkb = (const float*)d_in[15];

  if (ws_size < 112197632u) return;

  char* ws = (char*)d_ws;
  ushort* Xb   = (ushort*)(ws);                  // [4608][1024] bf16
  ushort* Wqkv = (ushort*)(ws + 9437184);        // [3072][1024] bf16
  ushort* Wo   = (ushort*)(ws + 15728640);       // [1024][1024] bf16
  float*  Y    = (float*)(ws + 17825792);        // [4608][3072] f32 (dead after lnrope)
  ushort* Vtb  = (ushort*)(ws + 17825792);       // [32][64][2304] bf16 (reuses Y space)
  ushort* Qb   = (ushort*)(ws + 74448896);       // [32][2304][64] bf16
  ushort* Kb   = (ushort*)(ws + 83886080);
  ushort* Vb   = (ushort*)(ws + 93323264);
  ushort* AO   = (ushort*)(ws + 102760448);      // [4608][1024] bf16

  float* out = (float*)d_out;

  k_prep_w<<<dim3(4096), dim3(256), 0, stream>>>(wq, wk, wv, wo, Wqkv, Wo);
  k_prep_x<<<dim3(4668), dim3(256), 0, stream>>>(hid, enc, Xb, AO);
  k_gemm<0><<<dim3(36 * 24), dim3(256), 0, stream>>>(Xb, Wqkv, Y, (float*)nullptr, (const float*)nullptr, 3072, 1024);
  k_lnrope<<<dim3(18432), dim3(256), 0, stream>>>(Y, bq, bk, bv, lnqw, lnqb, lnkw, lnkb, cosb, sinb, Qb, Kb, Vb);
  k_vt<<<dim3(32 * 36), dim3(256), 0, stream>>>(Vb, Vtb);   // Y dead from here; Vtb lives in its space
  k_attn<<<dim3(32 * 36), dim3(256), 0, stream>>>(Qb, Kb, Vtb, AO);
  k_gemm<1><<<dim3(36 * 8), dim3(256), 0, stream>>>(AO, Wo, (float*)nullptr, out, bo, 1024, 1024);
}

// Round 9
// 232.419 us; speedup vs baseline: 49.5124x; 1.0700x over previous
//
#include <hip/hip_runtime.h>
#include <hip/hip_bf16.h>

typedef __attribute__((ext_vector_type(4))) float f32x4;
typedef __attribute__((ext_vector_type(8))) short s16x8;
typedef __attribute__((ext_vector_type(4))) short s16x4;

#define GLOAD16(g, s) __builtin_amdgcn_global_load_lds((const __attribute__((address_space(1))) void*)(g), (__attribute__((address_space(3))) void*)(s), 16, 0, 0)

static constexpr int kB    = 2;
static constexpr int kSTXT = 226;
static constexpr int kSVID = 2048;
static constexpr int kD    = 1024;
static constexpr int kS    = kSTXT + kSVID;   // 2274
static constexpr int kBS   = kB * kS;         // 4548
static constexpr int kMPAD = 4608;            // 36*128
static constexpr int kSPAD = 2304;            // 36*64
static constexpr int kNT64 = kSPAD / 64;      // 36

static __device__ __forceinline__ ushort f2bf(float f) {
  unsigned u = __float_as_uint(f);
  u += 0x7fffu + ((u >> 16) & 1u);            // RNE (finite data only)
  return (ushort)(u >> 16);
}

static __device__ __forceinline__ unsigned cvt_pk_bf16(float lo, float hi) {
  unsigned r;
  asm("v_cvt_pk_bf16_f32 %0, %1, %2" : "=v"(r) : "v"(lo), "v"(hi));
  return r;
}

static __device__ __forceinline__ f32x4 mfma16(s16x8 a, s16x8 b, f32x4 c) {
  return __builtin_amdgcn_mfma_f32_16x16x32_bf16(a, b, c, 0, 0, 0);
}

// ---------------- prep: weights -> bf16 ----------------
__global__ __launch_bounds__(256) void k_prep_w(const float* __restrict__ wq, const float* __restrict__ wk,
                                                const float* __restrict__ wv, const float* __restrict__ wo,
                                                ushort* __restrict__ Wqkv, ushort* __restrict__ Wo) {
  int q = blockIdx.x * 256 + threadIdx.x;
  int reg = q >> 18;
  int off = (q & 262143) << 2;
  const float* sp = (reg == 0) ? wq : (reg == 1) ? wk : (reg == 2) ? wv : wo;
  float4 v = *(const float4*)(sp + off);
  ushort4 o;
  o.x = f2bf(v.x); o.y = f2bf(v.y); o.z = f2bf(v.z); o.w = f2bf(v.w);
  ushort* dst = (reg < 3) ? (Wqkv + ((size_t)reg << 20) + off) : (Wo + off);
  *(ushort4*)dst = o;
}

// ---------------- prep: X concat+cast, zero AO pad rows ----------------
__global__ __launch_bounds__(256) void k_prep_x(const float* __restrict__ hid, const float* __restrict__ enc,
                                                ushort* __restrict__ Xb, ushort* __restrict__ AO) {
  int q = blockIdx.x * 256 + threadIdx.x;
  const int XQ = (kMPAD * kD) / 4;
  if (q < XQ) {
    int row = q >> 8;
    int cq = (q & 255) << 2;
    ushort4 o;
    if (row < kBS) {
      int b = row / kS, s = row - b * kS;
      const float* src = (s < kSTXT) ? (enc + (size_t)(b * kSTXT + s) * kD + cq)
                                     : (hid + (size_t)(b * kSVID + (s - kSTXT)) * kD + cq);
      float4 v = *(const float4*)src;
      o.x = f2bf(v.x); o.y = f2bf(v.y); o.z = f2bf(v.z); o.w = f2bf(v.w);
    } else {
      o.x = 0; o.y = 0; o.z = 0; o.w = 0;
    }
    *(ushort4*)(Xb + (size_t)row * kD + cq) = o;
  } else {
    int p = q - XQ;
    ushort4 z; z.x = 0; z.y = 0; z.z = 0; z.w = 0;
    *(ushort4*)(AO + (size_t)kBS * kD + (size_t)p * 4) = z;
  }
}

// ---------------- bf16 GEMM, C = A * B^T ----------------
template<int EPI>
__global__ __launch_bounds__(256) void k_gemm(const ushort* __restrict__ A, const ushort* __restrict__ Bm,
                                              float* __restrict__ C, float* __restrict__ OutF,
                                              const float* __restrict__ bias, int N, int K) {
  __shared__ ushort lsA[4096];
  __shared__ ushort lsB[4096];
  int nt = N >> 7;
  int mt = blockIdx.x / nt, ntl = blockIdx.x - mt * nt;
  int m0 = mt << 7, n0 = ntl << 7;
  int tid = threadIdx.x;
  int w = tid >> 6, l = tid & 63;
  int wm = (w >> 1) << 6, wn = (w & 1) << 6;
  int lr = l & 15, lh = l >> 4;

  f32x4 acc[4][4] = {};

  for (int k0 = 0; k0 < K; k0 += 32) {
    __syncthreads();
#pragma unroll
    for (int i = 0; i < 2; ++i) {
      int c = i * 256 + w * 64 + l;
      GLOAD16(A + (size_t)(m0 + (c >> 2)) * K + k0 + ((c & 3) << 3),
              lsA + ((size_t)(i * 256 + w * 64) << 3));
      GLOAD16(Bm + (size_t)(n0 + (c >> 2)) * K + k0 + ((c & 3) << 3),
              lsB + ((size_t)(i * 256 + w * 64) << 3));
    }
    __syncthreads();
    s16x8 af[4], bfr[4];
#pragma unroll
    for (int mi = 0; mi < 4; ++mi) af[mi] = *(const s16x8*)&lsA[(wm + mi * 16 + lr) * 32 + lh * 8];
#pragma unroll
    for (int ni = 0; ni < 4; ++ni) bfr[ni] = *(const s16x8*)&lsB[(wn + ni * 16 + lr) * 32 + lh * 8];
#pragma unroll
    for (int mi = 0; mi < 4; ++mi)
#pragma unroll
      for (int ni = 0; ni < 4; ++ni)
        acc[mi][ni] = mfma16(af[mi], bfr[ni], acc[mi][ni]);
  }

#pragma unroll
  for (int mi = 0; mi < 4; ++mi) {
#pragma unroll
    for (int ni = 0; ni < 4; ++ni) {
#pragma unroll
      for (int r = 0; r < 4; ++r) {
        int row = m0 + wm + mi * 16 + lh * 4 + r;
        int col = n0 + wn + ni * 16 + lr;
        if (EPI == 0) {
          C[(size_t)row * N + col] = acc[mi][ni][r];
        } else {
          if (row < kBS) {
            float v = acc[mi][ni][r] + bias[col];
            int b = row / kS, s = row - b * kS;
            size_t o = (s >= kSTXT) ? ((size_t)(b * kSVID + s - kSTXT) * kD + col)
                                    : ((size_t)kB * kSVID * kD + (size_t)(b * kSTXT + s) * kD + col);
            OutF[o] = v;
          }
        }
      }
    }
  }
}

// ---------------- bias + per-head LN + RoPE -> Q/K/V bf16 panels [BH][SPAD][64] ----------------
// Q pre-scaled by (1/sqrt(64))*log2(e).
__global__ __launch_bounds__(256) void k_lnrope(const float* __restrict__ Y,
    const float* __restrict__ bq, const float* __restrict__ bk, const float* __restrict__ bv,
    const float* __restrict__ lnqw, const float* __restrict__ lnqb,
    const float* __restrict__ lnkw, const float* __restrict__ lnkb,
    const float* __restrict__ cosb, const float* __restrict__ sinb,
    ushort* __restrict__ Qo, ushort* __restrict__ Ko, ushort* __restrict__ Vo) {
  const float kQS = 0.125f * 1.4426950408889634f;
  int wid = (blockIdx.x * 256 + threadIdx.x) >> 6;
  int l = threadIdx.x & 63;
  int bh = wid / kSPAD;
  int s = wid - bh * kSPAD;
  size_t po = (size_t)wid * 64 + l;
  if (s >= kS) { Qo[po] = 0; Ko[po] = 0; Vo[po] = 0; return; }
  int b = bh >> 4, h = bh & 15;
  int row = b * kS + s;
  int col = h * 64 + l;
  const float* yr = Y + (size_t)row * 3072;
  float q = yr[col] + bq[col];
  float k = yr[1024 + col] + bk[col];
  float v = yr[2048 + col] + bv[col];
  float sq = q, sk = k;
#pragma unroll
  for (int m = 1; m < 64; m <<= 1) { sq += __shfl_xor(sq, m); sk += __shfl_xor(sk, m); }
  float dq = q - sq * (1.0f / 64.0f);
  float dk = k - sk * (1.0f / 64.0f);
  float vq = dq * dq, vk = dk * dk;
#pragma unroll
  for (int m = 1; m < 64; m <<= 1) { vq += __shfl_xor(vq, m); vk += __shfl_xor(vk, m); }
  q = dq * rsqrtf(vq * (1.0f / 64.0f) + 1e-5f) * lnqw[l] + lnqb[l];
  k = dk * rsqrtf(vk * (1.0f / 64.0f) + 1e-5f) * lnkw[l] + lnkb[l];
  if (s >= kSTXT) {
    int pos = s - kSTXT;
    float c = cosb[pos * 64 + l], sn = sinb[pos * 64 + l];
    float qp = __shfl_xor(q, 1), kp = __shfl_xor(k, 1);
    float sg = (l & 1) ? 1.0f : -1.0f;
    q = q * c + sg * qp * sn;
    k = k * c + sg * kp * sn;
  }
  Qo[po] = f2bf(q * kQS); Ko[po] = f2bf(k); Vo[po] = f2bf(v);
}

// ---------------- V transpose: Vb [bh][kSPAD][64] -> Vt [bh][64][kSPAD] ----------------
__global__ __launch_bounds__(256) void k_vt(const ushort* __restrict__ Vb, ushort* __restrict__ Vt) {
  __shared__ ushort lsT[64 * 68];
  int bid = blockIdx.x;                           // 32 bh * 36 s-blocks
  int bh = bid / 36, sb = bid - bh * 36;
  int s0 = sb * 64;
  const ushort* src = Vb + (size_t)bh * kSPAD * 64 + (size_t)s0 * 64;
  ushort* dst = Vt + (size_t)bh * 64 * kSPAD;
  int t = threadIdx.x;
#pragma unroll
  for (int i = 0; i < 4; ++i) {
    int q = i * 256 + t;
    int row = q >> 4, c4 = (q & 15) * 4;
    *(s16x4*)&lsT[row * 68 + c4] = *(const s16x4*)(src + (size_t)row * 64 + c4);
  }
  __syncthreads();
  int l = t & 63, wv = t >> 6;
#pragma unroll
  for (int c = 0; c < 16; ++c) {
    int d = wv * 16 + c;
    dst[(size_t)d * kSPAD + s0 + l] = lsT[l * 68 + d];
  }
}

// ---------------- flash attention (swapped ops, KVBLK=64, dbuf DMA, lean softmax) ----------------
__global__ __launch_bounds__(256) void k_attn(const ushort* __restrict__ Q, const ushort* __restrict__ K,
                                              const ushort* __restrict__ Vt, ushort* __restrict__ AO) {
  __shared__ ushort lsK[2][4096];          // [64 kv][64 d] XOR-swizzled
  __shared__ ushort lsVt[2][4096];         // [64 d][64 kv] XOR-swizzled
  __shared__ ushort lsP[4][2][16][40];     // per-wave P[q][k_local] per 32-half

  int bid = blockIdx.x;
  int wg = (bid & 7) * 144 + (bid >> 3);   // XCD swizzle
  int bh = wg / 36, qb = wg - bh * 36;
  const ushort* Qp = Q + (size_t)bh * kSPAD * 64;
  const char* Kg = (const char*)(K + (size_t)bh * kSPAD * 64);
  const char* Vg = (const char*)(Vt + (size_t)bh * 64 * kSPAD);

  int tid = threadIdx.x, w = tid >> 6, l = tid & 63;
  int lr = l & 15, lh = l >> 4;
  int q0 = qb * 64 + w * 16;

  s16x8 aq[2];                             // Q fragment (B-side): row q=lr
#pragma unroll
  for (int kk = 0; kk < 2; ++kk)
    aq[kk] = *(const s16x8*)(Qp + (size_t)(q0 + lr) * 64 + kk * 32 + lh * 8);

  f32x4 o[4] = {};                         // O^T frags
  float m = -1e30f, lsum = 0.0f;           // m row-uniform; lsum per-lane PARTIAL

  int c0 = w * 64 + l, c1 = c0 + 256;
  int kr0 = c0 >> 3, kr1 = c1 >> 3;
  int ksrc0 = (c0 * 16) ^ ((kr0 & 7) << 4);
  int ksrc1 = (c1 * 16) ^ ((kr1 & 7) << 4);
  int vsrc0 = kr0 * (kSPAD * 2) + (((c0 & 7) * 16) ^ ((kr0 & 7) << 4));
  int vsrc1 = kr1 * (kSPAD * 2) + (((c1 & 7) * 16) ^ ((kr1 & 7) << 4));

#define ISSUE_TILE(buf, t) do {                                              \
    GLOAD16(Kg + (size_t)(t) * 8192 + ksrc0, (char*)lsK[buf] + c0 * 16);     \
    GLOAD16(Kg + (size_t)(t) * 8192 + ksrc1, (char*)lsK[buf] + c1 * 16);     \
    GLOAD16(Vg + (size_t)(t) * 128 + vsrc0,  (char*)lsVt[buf] + c0 * 16);    \
    GLOAD16(Vg + (size_t)(t) * 128 + vsrc1,  (char*)lsVt[buf] + c1 * 16);    \
  } while (0)

  ISSUE_TILE(0, 0);

  for (int t = 0; t < kNT64; ++t) {
    int cur = t & 1;
    __builtin_amdgcn_s_barrier();
    if (t + 1 < kNT64) {
      ISSUE_TILE(cur ^ 1, t + 1);
      asm volatile("s_waitcnt vmcnt(4)" ::: "memory");
    } else {
      asm volatile("s_waitcnt vmcnt(0)" ::: "memory");
    }
    __builtin_amdgcn_s_barrier();
    __builtin_amdgcn_sched_barrier(0);

    // QK^T swapped: s[kb] = K-rows x Q -> S^T[k][q=lr]
    f32x4 s[4] = {};
    __builtin_amdgcn_s_setprio(1);
#pragma unroll
    for (int kk = 0; kk < 2; ++kk) {
#pragma unroll
      for (int kb = 0; kb < 4; ++kb) {
        int row = kb * 16 + lr;
        s16x8 bk8 = *(const s16x8*)((const char*)lsK[cur] +
                      ((row * 128 + kk * 64 + lh * 16) ^ ((lr & 7) << 4)));
        s[kb] = mfma16(bk8, aq[kk], s[kb]);
      }
    }
    __builtin_amdgcn_s_setprio(0);

    if (t == kNT64 - 1) {                  // mask tail k >= kS
      int kv0 = t * 64;
#pragma unroll
      for (int kb = 0; kb < 4; ++kb)
#pragma unroll
        for (int r = 0; r < 4; ++r)
          if (kv0 + kb * 16 + lh * 4 + r >= kS) s[kb][r] = -1e30f;
    }

    // softmax: per-lane partial max; ballot is equivalent to full-row check
    float pm = s[0][0];
#pragma unroll
    for (int kb = 0; kb < 4; ++kb)
#pragma unroll
      for (int r = 0; r < 4; ++r) pm = fmaxf(pm, s[kb][r]);
    if (!__all(pm <= m + 8.0f)) {          // rare: full reduce + rescale
      float pmf = fmaxf(pm, __shfl_xor(pm, 16));
      pmf = fmaxf(pmf, __shfl_xor(pmf, 32));
      float nm = fmaxf(m, pmf);
      float al = exp2f(m - nm);
      m = nm;
      lsum *= al;
#pragma unroll
      for (int db = 0; db < 4; ++db)
#pragma unroll
        for (int r = 0; r < 4; ++r) o[db][r] *= al;
    }
#pragma unroll
    for (int kb = 0; kb < 4; ++kb)
#pragma unroll
      for (int r = 0; r < 4; ++r) { s[kb][r] = exp2f(s[kb][r] - m); lsum += s[kb][r]; }

    // P[q=lr][k] -> lsP via packed cvt (1 VALU op per 2 values)
#pragma unroll
    for (int kb = 0; kb < 4; ++kb) {
      unsigned p01 = cvt_pk_bf16(s[kb][0], s[kb][1]);
      unsigned p23 = cvt_pk_bf16(s[kb][2], s[kb][3]);
      int half = kb >> 1, kloc = (kb & 1) * 16 + lh * 4;
      *(unsigned*)&lsP[w][half][lr][kloc] = p01;
      *(unsigned*)&lsP[w][half][lr][kloc + 2] = p23;
    }
    asm volatile("s_waitcnt lgkmcnt(0)" ::: "memory");
    __builtin_amdgcn_sched_barrier(0);

    // PV swapped: o[db] += V^T x P^T
    __builtin_amdgcn_s_setprio(1);
#pragma unroll
    for (int half = 0; half < 2; ++half) {
      s16x8 pa = *(const s16x8*)&lsP[w][half][lr][lh * 8];
#pragma unroll
      for (int db = 0; db < 4; ++db) {
        int d = db * 16 + lr;
        s16x8 bv = *(const s16x8*)((const char*)lsVt[cur] +
                     ((d * 128 + half * 64 + lh * 16) ^ ((lr & 7) << 4)));
        o[db] = mfma16(bv, pa, o[db]);
      }
    }
    __builtin_amdgcn_s_setprio(0);
  }
#undef ISSUE_TILE

  // reduce partial lsum across the 4 lanes sharing q-row lr
  lsum += __shfl_xor(lsum, 16);
  lsum += __shfl_xor(lsum, 32);

  int b = bh >> 4, h = bh & 15;
  int srow = q0 + lr;
  if (srow < kS) {
    float inv = 1.0f / lsum;
    size_t base = (size_t)(b * kS + srow) * kD + h * 64;
#pragma unroll
    for (int db = 0; db < 4; ++db)
#pragma unroll
      for (int r = 0; r < 4; ++r)
        AO[base + db * 16 + lh * 4 + r] = f2bf(o[db][r] * inv);
  }
}

// ---------------- launch ----------------
extern "C" void kernel_launch(void* const* d_in, const int* in_sizes, int n_in,
                              void* d_out, int out_size, void* d_ws, size_t ws_size,
                              hipStream_t stream) {
  const float* hid  = (const float*)d_in[0];
  const float* enc  = (const float*)d_in[1];
  const float* cosb = (const float*)d_in[2];
  const float* sinb = (const float*)d_in[3];
  const float* wq   = (const float*)d_in[4];
  const float* bq   = (const float*)d_in[5];
  const float* wk   = (const float*)d_in[6];
  const float* bk   = (const float*)d_in[7];
  const float* wv   = (const float*)d_in[8];
  const float* bv   = (const float*)d_in[9];
  const float* wo   = (const float*)d_in[10];
  const float* bo   = (const float*)d_in[11];
  const float* lnqw = (const float*)d_in[12];
  const float* lnqb = (const float*)d_in[13];
  const float* lnkw = (const float*)d_in[14];
  const float* lnkb = (const float*)d_in[15];

  if (ws_size < 112197632u) return;

  char* ws = (char*)d_ws;
  ushort* Xb   = (ushort*)(ws);                  // [4608][1024] bf16
  ushort* Wqkv = (ushort*)(ws + 9437184);        // [3072][1024] bf16
  ushort* Wo   = (ushort*)(ws + 15728640);       // [1024][1024] bf16
  float*  Y    = (float*)(ws + 17825792);        // [4608][3072] f32 (dead after lnrope)
  ushort* Vtb  = (ushort*)(ws + 17825792);       // [32][64][2304] bf16 (reuses Y space)
  ushort* Qb   = (ushort*)(ws + 74448896);       // [32][2304][64] bf16
  ushort* Kb   = (ushort*)(ws + 83886080);
  ushort* Vb   = (ushort*)(ws + 93323264);
  ushort* AO   = (ushort*)(ws + 102760448);      // [4608][1024] bf16

  float* out = (float*)d_out;

  k_prep_w<<<dim3(4096), dim3(256), 0, stream>>>(wq, wk, wv, wo, Wqkv, Wo);
  k_prep_x<<<dim3(4668), dim3(256), 0, stream>>>(hid, enc, Xb, AO);
  k_gemm<0><<<dim3(36 * 24), dim3(256), 0, stream>>>(Xb, Wqkv, Y, (float*)nullptr, (const float*)nullptr, 3072, 1024);
  k_lnrope<<<dim3(18432), dim3(256), 0, stream>>>(Y, bq, bk, bv, lnqw, lnqb, lnkw, lnkb, cosb, sinb, Qb, Kb, Vb);
  k_vt<<<dim3(32 * 36), dim3(256), 0, stream>>>(Vb, Vtb);
  k_attn<<<dim3(32 * 36), dim3(256), 0, stream>>>(Qb, Kb, Vtb, AO);
  k_gemm<1><<<dim3(36 * 8), dim3(256), 0, stream>>>(AO, Wo, (float*)nullptr, out, bo, 1024, 1024);
}

// Round 10
// 221.744 us; speedup vs baseline: 51.8962x; 1.0481x over previous
//
#include <hip/hip_runtime.h>
#include <hip/hip_bf16.h>

typedef __attribute__((ext_vector_type(4))) float f32x4;
typedef __attribute__((ext_vector_type(8))) short s16x8;
typedef __attribute__((ext_vector_type(4))) short s16x4;

#define GLOAD16(g, s) __builtin_amdgcn_global_load_lds((const __attribute__((address_space(1))) void*)(g), (__attribute__((address_space(3))) void*)(s), 16, 0, 0)

static constexpr int kB    = 2;
static constexpr int kSTXT = 226;
static constexpr int kSVID = 2048;
static constexpr int kD    = 1024;
static constexpr int kS    = kSTXT + kSVID;   // 2274
static constexpr int kBS   = kB * kS;         // 4548
static constexpr int kMPAD = 4608;            // 36*128
static constexpr int kSPAD = 2304;            // 36*64
static constexpr int kNT64 = kSPAD / 64;      // 36

static __device__ __forceinline__ ushort f2bf(float f) {
  unsigned u = __float_as_uint(f);
  u += 0x7fffu + ((u >> 16) & 1u);            // RNE (finite data only)
  return (ushort)(u >> 16);
}

static __device__ __forceinline__ unsigned cvt_pk_bf16(float lo, float hi) {
  unsigned r;
  asm("v_cvt_pk_bf16_f32 %0, %1, %2" : "=v"(r) : "v"(lo), "v"(hi));
  return r;
}

static __device__ __forceinline__ f32x4 mfma16(s16x8 a, s16x8 b, f32x4 c) {
  return __builtin_amdgcn_mfma_f32_16x16x32_bf16(a, b, c, 0, 0, 0);
}

// ---------------- prep: weights -> bf16 ----------------
__global__ __launch_bounds__(256) void k_prep_w(const float* __restrict__ wq, const float* __restrict__ wk,
                                                const float* __restrict__ wv, const float* __restrict__ wo,
                                                ushort* __restrict__ Wqkv, ushort* __restrict__ Wo) {
  int q = blockIdx.x * 256 + threadIdx.x;
  int reg = q >> 18;
  int off = (q & 262143) << 2;
  const float* sp = (reg == 0) ? wq : (reg == 1) ? wk : (reg == 2) ? wv : wo;
  float4 v = *(const float4*)(sp + off);
  ushort4 o;
  o.x = f2bf(v.x); o.y = f2bf(v.y); o.z = f2bf(v.z); o.w = f2bf(v.w);
  ushort* dst = (reg < 3) ? (Wqkv + ((size_t)reg << 20) + off) : (Wo + off);
  *(ushort4*)dst = o;
}

// ---------------- prep: X concat+cast, zero AO pad rows ----------------
__global__ __launch_bounds__(256) void k_prep_x(const float* __restrict__ hid, const float* __restrict__ enc,
                                                ushort* __restrict__ Xb, ushort* __restrict__ AO) {
  int q = blockIdx.x * 256 + threadIdx.x;
  const int XQ = (kMPAD * kD) / 4;
  if (q < XQ) {
    int row = q >> 8;
    int cq = (q & 255) << 2;
    ushort4 o;
    if (row < kBS) {
      int b = row / kS, s = row - b * kS;
      const float* src = (s < kSTXT) ? (enc + (size_t)(b * kSTXT + s) * kD + cq)
                                     : (hid + (size_t)(b * kSVID + (s - kSTXT)) * kD + cq);
      float4 v = *(const float4*)src;
      o.x = f2bf(v.x); o.y = f2bf(v.y); o.z = f2bf(v.z); o.w = f2bf(v.w);
    } else {
      o.x = 0; o.y = 0; o.z = 0; o.w = 0;
    }
    *(ushort4*)(Xb + (size_t)row * kD + cq) = o;
  } else {
    int p = q - XQ;
    ushort4 z; z.x = 0; z.y = 0; z.z = 0; z.w = 0;
    *(ushort4*)(AO + (size_t)kBS * kD + (size_t)p * 4) = z;
  }
}

// ---------------- zero panel pad rows: Q/K rows s in [2274,2304), Vt cols s in [2274,2304) ----------------
__global__ __launch_bounds__(256) void k_padz(ushort* __restrict__ Qb, ushort* __restrict__ Kb,
                                              ushort* __restrict__ Vt) {
  int id = blockIdx.x * 256 + threadIdx.x;       // 92160 u32 writes
  int region = id / 30720;
  int r = id - region * 30720;
  if (region < 2) {
    int bh = r / 960, off = r - bh * 960;        // 30 rows * 64 = 1920 elems = 960 u32 per bh
    unsigned* p = (unsigned*)((region == 0 ? Qb : Kb) + (size_t)bh * kSPAD * 64 + (size_t)kS * 64);
    p[off] = 0u;
  } else {
    int row = r / 15, off = r - row * 15;        // row = bh*64+d; 30 elems = 15 u32 per row
    unsigned* p = (unsigned*)(Vt + (size_t)row * kSPAD + kS);
    p[off] = 0u;
  }
}

// ---------------- fused QKV GEMM: X[M,1024] * Wqkv[3072,1024]^T + bias, LN, RoPE -> panels ----------------
// n0 < 1024: Q (pre-scaled); < 2048: K; else V (written transposed to Vt).
__global__ __launch_bounds__(256) void k_gemmqkv(const ushort* __restrict__ A, const ushort* __restrict__ Bm,
    const float* __restrict__ bq, const float* __restrict__ bk, const float* __restrict__ bv,
    const float* __restrict__ lnqw, const float* __restrict__ lnqb,
    const float* __restrict__ lnkw, const float* __restrict__ lnkb,
    const float* __restrict__ cosb, const float* __restrict__ sinb,
    ushort* __restrict__ Qb, ushort* __restrict__ Kb, ushort* __restrict__ Vt) {
  __shared__ ushort lsA[4096];
  __shared__ ushort lsB[4096];
  const int K = 1024, nt = 24;
  int mt = blockIdx.x / nt, ntl = blockIdx.x - mt * nt;
  int m0 = mt << 7, n0 = ntl << 7;
  int tid = threadIdx.x;
  int w = tid >> 6, l = tid & 63;
  int wm = (w >> 1) << 6, wn = (w & 1) << 6;
  int lr = l & 15, lh = l >> 4;

  f32x4 acc[4][4] = {};

  for (int k0 = 0; k0 < K; k0 += 32) {
    __syncthreads();
#pragma unroll
    for (int i = 0; i < 2; ++i) {
      int c = i * 256 + w * 64 + l;
      GLOAD16(A + (size_t)(m0 + (c >> 2)) * K + k0 + ((c & 3) << 3),
              lsA + ((size_t)(i * 256 + w * 64) << 3));
      GLOAD16(Bm + (size_t)(n0 + (c >> 2)) * K + k0 + ((c & 3) << 3),
              lsB + ((size_t)(i * 256 + w * 64) << 3));
    }
    __syncthreads();
    s16x8 af[4], bfr[4];
#pragma unroll
    for (int mi = 0; mi < 4; ++mi) af[mi] = *(const s16x8*)&lsA[(wm + mi * 16 + lr) * 32 + lh * 8];
#pragma unroll
    for (int ni = 0; ni < 4; ++ni) bfr[ni] = *(const s16x8*)&lsB[(wn + ni * 16 + lr) * 32 + lh * 8];
#pragma unroll
    for (int mi = 0; mi < 4; ++mi)
#pragma unroll
      for (int ni = 0; ni < 4; ++ni)
        acc[mi][ni] = mfma16(af[mi], bfr[ni], acc[mi][ni]);
  }

  // ---------- fused epilogue ----------
  int proj = n0 >> 10;                           // 0=Q, 1=K, 2=V
  int cip0 = (n0 & 1023) + wn;                   // col-in-projection base of this wave
  int hw = cip0 >> 6;                            // head of this wave's subtile
  const float* bias = (proj == 0) ? bq : (proj == 1) ? bk : bv;
  float bi[4];
#pragma unroll
  for (int ni = 0; ni < 4; ++ni) bi[ni] = bias[cip0 + ni * 16 + lr];

  if (proj < 2) {
    const float* lw = proj ? lnkw : lnqw;
    const float* lb = proj ? lnkb : lnqb;
    const float scale = proj ? 1.0f : 0.125f * 1.4426950408889634f;
    float w4[4], b4[4];
#pragma unroll
    for (int ni = 0; ni < 4; ++ni) { w4[ni] = lw[ni * 16 + lr]; b4[ni] = lb[ni * 16 + lr]; }
    ushort* panel = proj ? Kb : Qb;
#pragma unroll
    for (int mi = 0; mi < 4; ++mi) {
#pragma unroll
      for (int r = 0; r < 4; ++r) {
        int grow = m0 + wm + mi * 16 + lh * 4 + r;
        float v0 = acc[mi][0][r] + bi[0], v1 = acc[mi][1][r] + bi[1];
        float v2 = acc[mi][2][r] + bi[2], v3 = acc[mi][3][r] + bi[3];
        float sum = (v0 + v1) + (v2 + v3);
        sum += __shfl_xor(sum, 1); sum += __shfl_xor(sum, 2);
        sum += __shfl_xor(sum, 4); sum += __shfl_xor(sum, 8);
        float mu = sum * (1.0f / 64.0f);
        float d0 = v0 - mu, d1 = v1 - mu, d2 = v2 - mu, d3 = v3 - mu;
        float ss = (d0 * d0 + d1 * d1) + (d2 * d2 + d3 * d3);
        ss += __shfl_xor(ss, 1); ss += __shfl_xor(ss, 2);
        ss += __shfl_xor(ss, 4); ss += __shfl_xor(ss, 8);
        float rstd = rsqrtf(ss * (1.0f / 64.0f) + 1e-5f);
        float n0v = d0 * rstd * w4[0] + b4[0];
        float n1v = d1 * rstd * w4[1] + b4[1];
        float n2v = d2 * rstd * w4[2] + b4[2];
        float n3v = d3 * rstd * w4[3] + b4[3];
        int bb = grow >= kS;
        int s = grow - (bb ? kS : 0);
        bool valid = (grow < kBS) && (s < kS);   // row-uniform across the 16 lanes
        if (valid) {
          if (s >= kSTXT) {                      // RoPE (row-uniform branch)
            int pos = s - kSTXT;
            const float* cr = cosb + (size_t)pos * 64;
            const float* sr = sinb + (size_t)pos * 64;
            float sg = (lr & 1) ? 1.0f : -1.0f;
            float p0 = __shfl_xor(n0v, 1), p1 = __shfl_xor(n1v, 1);
            float p2 = __shfl_xor(n2v, 1), p3 = __shfl_xor(n3v, 1);
            n0v = n0v * cr[lr]      + sg * p0 * sr[lr];
            n1v = n1v * cr[16 + lr] + sg * p1 * sr[16 + lr];
            n2v = n2v * cr[32 + lr] + sg * p2 * sr[32 + lr];
            n3v = n3v * cr[48 + lr] + sg * p3 * sr[48 + lr];
          }
          ushort* pr = panel + (size_t)((bb << 4) + hw) * kSPAD * 64 + (size_t)s * 64;
          pr[lr]      = f2bf(n0v * scale);
          pr[16 + lr] = f2bf(n1v * scale);
          pr[32 + lr] = f2bf(n2v * scale);
          pr[48 + lr] = f2bf(n3v * scale);
        }
      }
    }
  } else {
    // V: bias add, transposed store Vt[bh][d][s]
    bool fast = (m0 != 2176) && (m0 != 4480);    // tiles straddling b-boundary(2274)/pad(4548)
#pragma unroll
    for (int mi = 0; mi < 4; ++mi) {
      int grow0 = m0 + wm + mi * 16 + lh * 4;    // 4 consecutive rows
#pragma unroll
      for (int ni = 0; ni < 4; ++ni) {
        int d = ni * 16 + lr;
        float f0 = acc[mi][ni][0] + bi[ni], f1 = acc[mi][ni][1] + bi[ni];
        float f2 = acc[mi][ni][2] + bi[ni], f3 = acc[mi][ni][3] + bi[ni];
        if (fast) {
          int bb = grow0 >= kS;
          int s0 = grow0 - (bb ? kS : 0);
          unsigned* pr = (unsigned*)(Vt + (size_t)((bb << 4) + hw) * 64 * kSPAD + (size_t)d * kSPAD + s0);
          pr[0] = cvt_pk_bf16(f0, f1);
          pr[1] = cvt_pk_bf16(f2, f3);
        } else {
          float fv[4] = {f0, f1, f2, f3};
#pragma unroll
          for (int j = 0; j < 4; ++j) {
            int grow = grow0 + j;
            int bb = grow >= kS;
            int s = grow - (bb ? kS : 0);
            if (grow < kBS && s < kS)
              Vt[(size_t)((bb << 4) + hw) * 64 * kSPAD + (size_t)d * kSPAD + s] = f2bf(fv[j]);
          }
        }
      }
    }
  }
}

// ---------------- out-projection GEMM: out = AO * Wo^T + bo, permuted (video-first) f32 store ----------------
__global__ __launch_bounds__(256) void k_gemmo(const ushort* __restrict__ A, const ushort* __restrict__ Bm,
                                               float* __restrict__ OutF, const float* __restrict__ bias) {
  __shared__ ushort lsA[4096];
  __shared__ ushort lsB[4096];
  const int K = 1024, N = 1024, nt = 8;
  int mt = blockIdx.x / nt, ntl = blockIdx.x - mt * nt;
  int m0 = mt << 7, n0 = ntl << 7;
  int tid = threadIdx.x;
  int w = tid >> 6, l = tid & 63;
  int wm = (w >> 1) << 6, wn = (w & 1) << 6;
  int lr = l & 15, lh = l >> 4;

  f32x4 acc[4][4] = {};

  for (int k0 = 0; k0 < K; k0 += 32) {
    __syncthreads();
#pragma unroll
    for (int i = 0; i < 2; ++i) {
      int c = i * 256 + w * 64 + l;
      GLOAD16(A + (size_t)(m0 + (c >> 2)) * K + k0 + ((c & 3) << 3),
              lsA + ((size_t)(i * 256 + w * 64) << 3));
      GLOAD16(Bm + (size_t)(n0 + (c >> 2)) * K + k0 + ((c & 3) << 3),
              lsB + ((size_t)(i * 256 + w * 64) << 3));
    }
    __syncthreads();
    s16x8 af[4], bfr[4];
#pragma unroll
    for (int mi = 0; mi < 4; ++mi) af[mi] = *(const s16x8*)&lsA[(wm + mi * 16 + lr) * 32 + lh * 8];
#pragma unroll
    for (int ni = 0; ni < 4; ++ni) bfr[ni] = *(const s16x8*)&lsB[(wn + ni * 16 + lr) * 32 + lh * 8];
#pragma unroll
    for (int mi = 0; mi < 4; ++mi)
#pragma unroll
      for (int ni = 0; ni < 4; ++ni)
        acc[mi][ni] = mfma16(af[mi], bfr[ni], acc[mi][ni]);
  }

#pragma unroll
  for (int mi = 0; mi < 4; ++mi) {
#pragma unroll
    for (int ni = 0; ni < 4; ++ni) {
#pragma unroll
      for (int r = 0; r < 4; ++r) {
        int row = m0 + wm + mi * 16 + lh * 4 + r;
        int col = n0 + wn + ni * 16 + lr;
        if (row < kBS) {
          float v = acc[mi][ni][r] + bias[col];
          int b = row / kS, s = row - b * kS;
          size_t o = (s >= kSTXT) ? ((size_t)(b * kSVID + s - kSTXT) * kD + col)
                                  : ((size_t)kB * kSVID * kD + (size_t)(b * kSTXT + s) * kD + col);
          OutF[o] = v;
        }
      }
    }
  }
}

// ---------------- flash attention (unchanged from round 9) ----------------
__global__ __launch_bounds__(256) void k_attn(const ushort* __restrict__ Q, const ushort* __restrict__ K,
                                              const ushort* __restrict__ Vt, ushort* __restrict__ AO) {
  __shared__ ushort lsK[2][4096];          // [64 kv][64 d] XOR-swizzled
  __shared__ ushort lsVt[2][4096];         // [64 d][64 kv] XOR-swizzled
  __shared__ ushort lsP[4][2][16][40];     // per-wave P[q][k_local] per 32-half

  int bid = blockIdx.x;
  int wg = (bid & 7) * 144 + (bid >> 3);   // XCD swizzle
  int bh = wg / 36, qb = wg - bh * 36;
  const ushort* Qp = Q + (size_t)bh * kSPAD * 64;
  const char* Kg = (const char*)(K + (size_t)bh * kSPAD * 64);
  const char* Vg = (const char*)(Vt + (size_t)bh * 64 * kSPAD);

  int tid = threadIdx.x, w = tid >> 6, l = tid & 63;
  int lr = l & 15, lh = l >> 4;
  int q0 = qb * 64 + w * 16;

  s16x8 aq[2];
#pragma unroll
  for (int kk = 0; kk < 2; ++kk)
    aq[kk] = *(const s16x8*)(Qp + (size_t)(q0 + lr) * 64 + kk * 32 + lh * 8);

  f32x4 o[4] = {};
  float m = -1e30f, lsum = 0.0f;

  int c0 = w * 64 + l, c1 = c0 + 256;
  int kr0 = c0 >> 3, kr1 = c1 >> 3;
  int ksrc0 = (c0 * 16) ^ ((kr0 & 7) << 4);
  int ksrc1 = (c1 * 16) ^ ((kr1 & 7) << 4);
  int vsrc0 = kr0 * (kSPAD * 2) + (((c0 & 7) * 16) ^ ((kr0 & 7) << 4));
  int vsrc1 = kr1 * (kSPAD * 2) + (((c1 & 7) * 16) ^ ((kr1 & 7) << 4));

#define ISSUE_TILE(buf, t) do {                                              \
    GLOAD16(Kg + (size_t)(t) * 8192 + ksrc0, (char*)lsK[buf] + c0 * 16);     \
    GLOAD16(Kg + (size_t)(t) * 8192 + ksrc1, (char*)lsK[buf] + c1 * 16);     \
    GLOAD16(Vg + (size_t)(t) * 128 + vsrc0,  (char*)lsVt[buf] + c0 * 16);    \
    GLOAD16(Vg + (size_t)(t) * 128 + vsrc1,  (char*)lsVt[buf] + c1 * 16);    \
  } while (0)

  ISSUE_TILE(0, 0);

  for (int t = 0; t < kNT64; ++t) {
    int cur = t & 1;
    __builtin_amdgcn_s_barrier();
    if (t + 1 < kNT64) {
      ISSUE_TILE(cur ^ 1, t + 1);
      asm volatile("s_waitcnt vmcnt(4)" ::: "memory");
    } else {
      asm volatile("s_waitcnt vmcnt(0)" ::: "memory");
    }
    __builtin_amdgcn_s_barrier();
    __builtin_amdgcn_sched_barrier(0);

    f32x4 s[4] = {};
    __builtin_amdgcn_s_setprio(1);
#pragma unroll
    for (int kk = 0; kk < 2; ++kk) {
#pragma unroll
      for (int kb = 0; kb < 4; ++kb) {
        int row = kb * 16 + lr;
        s16x8 bk8 = *(const s16x8*)((const char*)lsK[cur] +
                      ((row * 128 + kk * 64 + lh * 16) ^ ((lr & 7) << 4)));
        s[kb] = mfma16(bk8, aq[kk], s[kb]);
      }
    }
    __builtin_amdgcn_s_setprio(0);

    if (t == kNT64 - 1) {
      int kv0 = t * 64;
#pragma unroll
      for (int kb = 0; kb < 4; ++kb)
#pragma unroll
        for (int r = 0; r < 4; ++r)
          if (kv0 + kb * 16 + lh * 4 + r >= kS) s[kb][r] = -1e30f;
    }

    float pm = s[0][0];
#pragma unroll
    for (int kb = 0; kb < 4; ++kb)
#pragma unroll
      for (int r = 0; r < 4; ++r) pm = fmaxf(pm, s[kb][r]);
    if (!__all(pm <= m + 8.0f)) {
      float pmf = fmaxf(pm, __shfl_xor(pm, 16));
      pmf = fmaxf(pmf, __shfl_xor(pmf, 32));
      float nm = fmaxf(m, pmf);
      float al = exp2f(m - nm);
      m = nm;
      lsum *= al;
#pragma unroll
      for (int db = 0; db < 4; ++db)
#pragma unroll
        for (int r = 0; r < 4; ++r) o[db][r] *= al;
    }
#pragma unroll
    for (int kb = 0; kb < 4; ++kb)
#pragma unroll
      for (int r = 0; r < 4; ++r) { s[kb][r] = exp2f(s[kb][r] - m); lsum += s[kb][r]; }

#pragma unroll
    for (int kb = 0; kb < 4; ++kb) {
      unsigned p01 = cvt_pk_bf16(s[kb][0], s[kb][1]);
      unsigned p23 = cvt_pk_bf16(s[kb][2], s[kb][3]);
      int half = kb >> 1, kloc = (kb & 1) * 16 + lh * 4;
      *(unsigned*)&lsP[w][half][lr][kloc] = p01;
      *(unsigned*)&lsP[w][half][lr][kloc + 2] = p23;
    }
    asm volatile("s_waitcnt lgkmcnt(0)" ::: "memory");
    __builtin_amdgcn_sched_barrier(0);

    __builtin_amdgcn_s_setprio(1);
#pragma unroll
    for (int half = 0; half < 2; ++half) {
      s16x8 pa = *(const s16x8*)&lsP[w][half][lr][lh * 8];
#pragma unroll
      for (int db = 0; db < 4; ++db) {
        int d = db * 16 + lr;
        s16x8 bv = *(const s16x8*)((const char*)lsVt[cur] +
                     ((d * 128 + half * 64 + lh * 16) ^ ((lr & 7) << 4)));
        o[db] = mfma16(bv, pa, o[db]);
      }
    }
    __builtin_amdgcn_s_setprio(0);
  }
#undef ISSUE_TILE

  lsum += __shfl_xor(lsum, 16);
  lsum += __shfl_xor(lsum, 32);

  int b = bh >> 4, h = bh & 15;
  int srow = q0 + lr;
  if (srow < kS) {
    float inv = 1.0f / lsum;
    size_t base = (size_t)(b * kS + srow) * kD + h * 64;
#pragma unroll
    for (int db = 0; db < 4; ++db)
#pragma unroll
      for (int r = 0; r < 4; ++r)
        AO[base + db * 16 + lh * 4 + r] = f2bf(o[db][r] * inv);
  }
}

// ---------------- launch ----------------
extern "C" void kernel_launch(void* const* d_in, const int* in_sizes, int n_in,
                              void* d_out, int out_size, void* d_ws, size_t ws_size,
                              hipStream_t stream) {
  const float* hid  = (const float*)d_in[0];
  const float* enc  = (const float*)d_in[1];
  const float* cosb = (const float*)d_in[2];
  const float* sinb = (const float*)d_in[3];
  const float* wq   = (const float*)d_in[4];
  const float* bq   = (const float*)d_in[5];
  const float* wk   = (const float*)d_in[6];
  const float* bk   = (const float*)d_in[7];
  const float* wv   = (const float*)d_in[8];
  const float* bv   = (const float*)d_in[9];
  const float* wo   = (const float*)d_in[10];
  const float* bo   = (const float*)d_in[11];
  const float* lnqw = (const float*)d_in[12];
  const float* lnqb = (const float*)d_in[13];
  const float* lnkw = (const float*)d_in[14];
  const float* lnkb = (const float*)d_in[15];

  if (ws_size < 112197632u) return;

  char* ws = (char*)d_ws;
  ushort* Xb   = (ushort*)(ws);                  // [4608][1024] bf16
  ushort* Wqkv = (ushort*)(ws + 9437184);        // [3072][1024] bf16
  ushort* Wo   = (ushort*)(ws + 15728640);       // [1024][1024] bf16
  ushort* Vtb  = (ushort*)(ws + 17825792);       // [32][64][2304] bf16
  ushort* Qb   = (ushort*)(ws + 74448896);       // [32][2304][64] bf16
  ushort* Kb   = (ushort*)(ws + 83886080);       // [32][2304][64] bf16
  ushort* AO   = (ushort*)(ws + 102760448);      // [4608][1024] bf16

  float* out = (float*)d_out;

  k_prep_w<<<dim3(4096), dim3(256), 0, stream>>>(wq, wk, wv, wo, Wqkv, Wo);
  k_prep_x<<<dim3(4668), dim3(256), 0, stream>>>(hid, enc, Xb, AO);
  k_padz<<<dim3(360), dim3(256), 0, stream>>>(Qb, Kb, Vtb);
  k_gemmqkv<<<dim3(36 * 24), dim3(256), 0, stream>>>(Xb, Wqkv, bq, bk, bv,
      lnqw, lnqb, lnkw, lnkb, cosb, sinb, Qb, Kb, Vtb);
  k_attn<<<dim3(32 * 36), dim3(256), 0, stream>>>(Qb, Kb, Vtb, AO);
  k_gemmo<<<dim3(36 * 8), dim3(256), 0, stream>>>(AO, Wo, out, bo);
}

// Round 11
// 221.515 us; speedup vs baseline: 51.9496x; 1.0010x over previous
//
#include <hip/hip_runtime.h>
#include <hip/hip_bf16.h>

typedef __attribute__((ext_vector_type(4))) float f32x4;
typedef __attribute__((ext_vector_type(8))) short s16x8;
typedef __attribute__((ext_vector_type(4))) short s16x4;

#define GLOAD16(g, s) __builtin_amdgcn_global_load_lds((const __attribute__((address_space(1))) void*)(g), (__attribute__((address_space(3))) void*)(s), 16, 0, 0)

static constexpr int kB    = 2;
static constexpr int kSTXT = 226;
static constexpr int kSVID = 2048;
static constexpr int kD    = 1024;
static constexpr int kS    = kSTXT + kSVID;   // 2274
static constexpr int kBS   = kB * kS;         // 4548
static constexpr int kMPAD = 4608;            // 36*128
static constexpr int kSPAD = 2304;            // 36*64
static constexpr int kNT64 = kSPAD / 64;      // 36

static __device__ __forceinline__ ushort f2bf(float f) {
  unsigned u = __float_as_uint(f);
  u += 0x7fffu + ((u >> 16) & 1u);            // RNE (finite data only)
  return (ushort)(u >> 16);
}

static __device__ __forceinline__ unsigned cvt_pk_bf16(float lo, float hi) {
  unsigned r;
  asm("v_cvt_pk_bf16_f32 %0, %1, %2" : "=v"(r) : "v"(lo), "v"(hi));
  return r;
}

static __device__ __forceinline__ f32x4 mfma16(s16x8 a, s16x8 b, f32x4 c) {
  return __builtin_amdgcn_mfma_f32_16x16x32_bf16(a, b, c, 0, 0, 0);
}

// ---------------- prep: weights -> bf16 ----------------
__global__ __launch_bounds__(256) void k_prep_w(const float* __restrict__ wq, const float* __restrict__ wk,
                                                const float* __restrict__ wv, const float* __restrict__ wo,
                                                ushort* __restrict__ Wqkv, ushort* __restrict__ Wo) {
  int q = blockIdx.x * 256 + threadIdx.x;
  int reg = q >> 18;
  int off = (q & 262143) << 2;
  const float* sp = (reg == 0) ? wq : (reg == 1) ? wk : (reg == 2) ? wv : wo;
  float4 v = *(const float4*)(sp + off);
  ushort4 o;
  o.x = f2bf(v.x); o.y = f2bf(v.y); o.z = f2bf(v.z); o.w = f2bf(v.w);
  ushort* dst = (reg < 3) ? (Wqkv + ((size_t)reg << 20) + off) : (Wo + off);
  *(ushort4*)dst = o;
}

// ---------------- prep: X concat+cast, zero AO pad rows ----------------
__global__ __launch_bounds__(256) void k_prep_x(const float* __restrict__ hid, const float* __restrict__ enc,
                                                ushort* __restrict__ Xb, ushort* __restrict__ AO) {
  int q = blockIdx.x * 256 + threadIdx.x;
  const int XQ = (kMPAD * kD) / 4;
  if (q < XQ) {
    int row = q >> 8;
    int cq = (q & 255) << 2;
    ushort4 o;
    if (row < kBS) {
      int b = row / kS, s = row - b * kS;
      const float* src = (s < kSTXT) ? (enc + (size_t)(b * kSTXT + s) * kD + cq)
                                     : (hid + (size_t)(b * kSVID + (s - kSTXT)) * kD + cq);
      float4 v = *(const float4*)src;
      o.x = f2bf(v.x); o.y = f2bf(v.y); o.z = f2bf(v.z); o.w = f2bf(v.w);
    } else {
      o.x = 0; o.y = 0; o.z = 0; o.w = 0;
    }
    *(ushort4*)(Xb + (size_t)row * kD + cq) = o;
  } else {
    int p = q - XQ;
    ushort4 z; z.x = 0; z.y = 0; z.z = 0; z.w = 0;
    *(ushort4*)(AO + (size_t)kBS * kD + (size_t)p * 4) = z;
  }
}

// ---------------- zero panel pad rows: Q/K rows s in [2274,2304), Vt cols s in [2274,2304) ----------------
__global__ __launch_bounds__(256) void k_padz(ushort* __restrict__ Qb, ushort* __restrict__ Kb,
                                              ushort* __restrict__ Vt) {
  int id = blockIdx.x * 256 + threadIdx.x;       // 92160 u32 writes
  int region = id / 30720;
  int r = id - region * 30720;
  if (region < 2) {
    int bh = r / 960, off = r - bh * 960;        // 30 rows * 64 = 1920 elems = 960 u32 per bh
    unsigned* p = (unsigned*)((region == 0 ? Qb : Kb) + (size_t)bh * kSPAD * 64 + (size_t)kS * 64);
    p[off] = 0u;
  } else {
    int row = r / 15, off = r - row * 15;        // row = bh*64+d; 30 elems = 15 u32 per row
    unsigned* p = (unsigned*)(Vt + (size_t)row * kSPAD + kS);
    p[off] = 0u;
  }
}

// ---------------- fused QKV GEMM: X[M,1024] * Wqkv[3072,1024]^T + bias, LN, RoPE -> panels ----------------
// n0 < 1024: Q (pre-scaled); < 2048: K; else V (written transposed to Vt).
__global__ __launch_bounds__(256) void k_gemmqkv(const ushort* __restrict__ A, const ushort* __restrict__ Bm,
    const float* __restrict__ bq, const float* __restrict__ bk, const float* __restrict__ bv,
    const float* __restrict__ lnqw, const float* __restrict__ lnqb,
    const float* __restrict__ lnkw, const float* __restrict__ lnkb,
    const float* __restrict__ cosb, const float* __restrict__ sinb,
    ushort* __restrict__ Qb, ushort* __restrict__ Kb, ushort* __restrict__ Vt) {
  __shared__ ushort lsA[4096];
  __shared__ ushort lsB[4096];
  const int K = 1024, nt = 24;
  int mt = blockIdx.x / nt, ntl = blockIdx.x - mt * nt;
  int m0 = mt << 7, n0 = ntl << 7;
  int tid = threadIdx.x;
  int w = tid >> 6, l = tid & 63;
  int wm = (w >> 1) << 6, wn = (w & 1) << 6;
  int lr = l & 15, lh = l >> 4;

  f32x4 acc[4][4] = {};

  for (int k0 = 0; k0 < K; k0 += 32) {
    __syncthreads();
#pragma unroll
    for (int i = 0; i < 2; ++i) {
      int c = i * 256 + w * 64 + l;
      GLOAD16(A + (size_t)(m0 + (c >> 2)) * K + k0 + ((c & 3) << 3),
              lsA + ((size_t)(i * 256 + w * 64) << 3));
      GLOAD16(Bm + (size_t)(n0 + (c >> 2)) * K + k0 + ((c & 3) << 3),
              lsB + ((size_t)(i * 256 + w * 64) << 3));
    }
    __syncthreads();
    s16x8 af[4], bfr[4];
#pragma unroll
    for (int mi = 0; mi < 4; ++mi) af[mi] = *(const s16x8*)&lsA[(wm + mi * 16 + lr) * 32 + lh * 8];
#pragma unroll
    for (int ni = 0; ni < 4; ++ni) bfr[ni] = *(const s16x8*)&lsB[(wn + ni * 16 + lr) * 32 + lh * 8];
#pragma unroll
    for (int mi = 0; mi < 4; ++mi)
#pragma unroll
      for (int ni = 0; ni < 4; ++ni)
        acc[mi][ni] = mfma16(af[mi], bfr[ni], acc[mi][ni]);
  }

  // ---------- fused epilogue ----------
  int proj = n0 >> 10;                           // 0=Q, 1=K, 2=V
  int cip0 = (n0 & 1023) + wn;                   // col-in-projection base of this wave
  int hw = cip0 >> 6;                            // head of this wave's subtile
  const float* bias = (proj == 0) ? bq : (proj == 1) ? bk : bv;
  float bi[4];
#pragma unroll
  for (int ni = 0; ni < 4; ++ni) bi[ni] = bias[cip0 + ni * 16 + lr];

  if (proj < 2) {
    const float* lw = proj ? lnkw : lnqw;
    const float* lb = proj ? lnkb : lnqb;
    const float scale = proj ? 1.0f : 0.125f * 1.4426950408889634f;
    float w4[4], b4[4];
#pragma unroll
    for (int ni = 0; ni < 4; ++ni) { w4[ni] = lw[ni * 16 + lr]; b4[ni] = lb[ni * 16 + lr]; }
    ushort* panel = proj ? Kb : Qb;
#pragma unroll
    for (int mi = 0; mi < 4; ++mi) {
#pragma unroll
      for (int r = 0; r < 4; ++r) {
        int grow = m0 + wm + mi * 16 + lh * 4 + r;
        float v0 = acc[mi][0][r] + bi[0], v1 = acc[mi][1][r] + bi[1];
        float v2 = acc[mi][2][r] + bi[2], v3 = acc[mi][3][r] + bi[3];
        float sum = (v0 + v1) + (v2 + v3);
        sum += __shfl_xor(sum, 1); sum += __shfl_xor(sum, 2);
        sum += __shfl_xor(sum, 4); sum += __shfl_xor(sum, 8);
        float mu = sum * (1.0f / 64.0f);
        float d0 = v0 - mu, d1 = v1 - mu, d2 = v2 - mu, d3 = v3 - mu;
        float ss = (d0 * d0 + d1 * d1) + (d2 * d2 + d3 * d3);
        ss += __shfl_xor(ss, 1); ss += __shfl_xor(ss, 2);
        ss += __shfl_xor(ss, 4); ss += __shfl_xor(ss, 8);
        float rstd = rsqrtf(ss * (1.0f / 64.0f) + 1e-5f);
        float n0v = d0 * rstd * w4[0] + b4[0];
        float n1v = d1 * rstd * w4[1] + b4[1];
        float n2v = d2 * rstd * w4[2] + b4[2];
        float n3v = d3 * rstd * w4[3] + b4[3];
        int bb = grow >= kS;
        int s = grow - (bb ? kS : 0);
        bool valid = (grow < kBS) && (s < kS);   // row-uniform across the 16 lanes
        if (valid) {
          if (s >= kSTXT) {                      // RoPE (row-uniform branch)
            int pos = s - kSTXT;
            const float* cr = cosb + (size_t)pos * 64;
            const float* sr = sinb + (size_t)pos * 64;
            float sg = (lr & 1) ? 1.0f : -1.0f;
            float p0 = __shfl_xor(n0v, 1), p1 = __shfl_xor(n1v, 1);
            float p2 = __shfl_xor(n2v, 1), p3 = __shfl_xor(n3v, 1);
            n0v = n0v * cr[lr]      + sg * p0 * sr[lr];
            n1v = n1v * cr[16 + lr] + sg * p1 * sr[16 + lr];
            n2v = n2v * cr[32 + lr] + sg * p2 * sr[32 + lr];
            n3v = n3v * cr[48 + lr] + sg * p3 * sr[48 + lr];
          }
          ushort* pr = panel + (size_t)((bb << 4) + hw) * kSPAD * 64 + (size_t)s * 64;
          pr[lr]      = f2bf(n0v * scale);
          pr[16 + lr] = f2bf(n1v * scale);
          pr[32 + lr] = f2bf(n2v * scale);
          pr[48 + lr] = f2bf(n3v * scale);
        }
      }
    }
  } else {
    // V: bias add, transposed store Vt[bh][d][s]
    bool fast = (m0 != 2176) && (m0 != 4480);    // tiles straddling b-boundary(2274)/pad(4548)
#pragma unroll
    for (int mi = 0; mi < 4; ++mi) {
      int grow0 = m0 + wm + mi * 16 + lh * 4;    // 4 consecutive rows
#pragma unroll
      for (int ni = 0; ni < 4; ++ni) {
        int d = ni * 16 + lr;
        float f0 = acc[mi][ni][0] + bi[ni], f1 = acc[mi][ni][1] + bi[ni];
        float f2 = acc[mi][ni][2] + bi[ni], f3 = acc[mi][ni][3] + bi[ni];
        if (fast) {
          int bb = grow0 >= kS;
          int s0 = grow0 - (bb ? kS : 0);
          unsigned* pr = (unsigned*)(Vt + (size_t)((bb << 4) + hw) * 64 * kSPAD + (size_t)d * kSPAD + s0);
          pr[0] = cvt_pk_bf16(f0, f1);
          pr[1] = cvt_pk_bf16(f2, f3);
        } else {
          float fv[4] = {f0, f1, f2, f3};
#pragma unroll
          for (int j = 0; j < 4; ++j) {
            int grow = grow0 + j;
            int bb = grow >= kS;
            int s = grow - (bb ? kS : 0);
            if (grow < kBS && s < kS)
              Vt[(size_t)((bb << 4) + hw) * 64 * kSPAD + (size_t)d * kSPAD + s] = f2bf(fv[j]);
          }
        }
      }
    }
  }
}

// ---------------- out-projection GEMM: out = AO * Wo^T + bo, permuted (video-first) f32 store ----------------
__global__ __launch_bounds__(256) void k_gemmo(const ushort* __restrict__ A, const ushort* __restrict__ Bm,
                                               float* __restrict__ OutF, const float* __restrict__ bias) {
  __shared__ ushort lsA[4096];
  __shared__ ushort lsB[4096];
  const int K = 1024, N = 1024, nt = 8;
  int mt = blockIdx.x / nt, ntl = blockIdx.x - mt * nt;
  int m0 = mt << 7, n0 = ntl << 7;
  int tid = threadIdx.x;
  int w = tid >> 6, l = tid & 63;
  int wm = (w >> 1) << 6, wn = (w & 1) << 6;
  int lr = l & 15, lh = l >> 4;

  f32x4 acc[4][4] = {};

  for (int k0 = 0; k0 < K; k0 += 32) {
    __syncthreads();
#pragma unroll
    for (int i = 0; i < 2; ++i) {
      int c = i * 256 + w * 64 + l;
      GLOAD16(A + (size_t)(m0 + (c >> 2)) * K + k0 + ((c & 3) << 3),
              lsA + ((size_t)(i * 256 + w * 64) << 3));
      GLOAD16(Bm + (size_t)(n0 + (c >> 2)) * K + k0 + ((c & 3) << 3),
              lsB + ((size_t)(i * 256 + w * 64) << 3));
    }
    __syncthreads();
    s16x8 af[4], bfr[4];
#pragma unroll
    for (int mi = 0; mi < 4; ++mi) af[mi] = *(const s16x8*)&lsA[(wm + mi * 16 + lr) * 32 + lh * 8];
#pragma unroll
    for (int ni = 0; ni < 4; ++ni) bfr[ni] = *(const s16x8*)&lsB[(wn + ni * 16 + lr) * 32 + lh * 8];
#pragma unroll
    for (int mi = 0; mi < 4; ++mi)
#pragma unroll
      for (int ni = 0; ni < 4; ++ni)
        acc[mi][ni] = mfma16(af[mi], bfr[ni], acc[mi][ni]);
  }

#pragma unroll
  for (int mi = 0; mi < 4; ++mi) {
#pragma unroll
    for (int ni = 0; ni < 4; ++ni) {
#pragma unroll
      for (int r = 0; r < 4; ++r) {
        int row = m0 + wm + mi * 16 + lh * 4 + r;
        int col = n0 + wn + ni * 16 + lr;
        if (row < kBS) {
          float v = acc[mi][ni][r] + bias[col];
          int b = row / kS, s = row - b * kS;
          size_t o = (s >= kSTXT) ? ((size_t)(b * kSVID + s - kSTXT) * kD + col)
                                  : ((size_t)kB * kSVID * kD + (size_t)(b * kSTXT + s) * kD + col);
          OutF[o] = v;
        }
      }
    }
  }
}

// ---------------- flash attention (bpermute P-transpose; LDS 32KB -> 5 blocks/CU) ----------------
__global__ __launch_bounds__(256, 5) void k_attn(const ushort* __restrict__ Q, const ushort* __restrict__ K,
                                                 const ushort* __restrict__ Vt, ushort* __restrict__ AO) {
  __shared__ ushort lsK[2][4096];          // [64 kv][64 d] XOR-swizzled
  __shared__ ushort lsVt[2][4096];         // [64 d][64 kv] XOR-swizzled

  int bid = blockIdx.x;
  int wg = (bid & 7) * 144 + (bid >> 3);   // XCD swizzle
  int bh = wg / 36, qb = wg - bh * 36;
  const ushort* Qp = Q + (size_t)bh * kSPAD * 64;
  const char* Kg = (const char*)(K + (size_t)bh * kSPAD * 64);
  const char* Vg = (const char*)(Vt + (size_t)bh * 64 * kSPAD);

  int tid = threadIdx.x, w = tid >> 6, l = tid & 63;
  int lr = l & 15, lh = l >> 4;
  int q0 = qb * 64 + w * 16;

  s16x8 aq[2];
#pragma unroll
  for (int kk = 0; kk < 2; ++kk)
    aq[kk] = *(const s16x8*)(Qp + (size_t)(q0 + lr) * 64 + kk * 32 + lh * 8);

  f32x4 o[4] = {};
  float m = -1e30f, lsum = 0.0f;

  int c0 = w * 64 + l, c1 = c0 + 256;
  int kr0 = c0 >> 3, kr1 = c1 >> 3;
  int ksrc0 = (c0 * 16) ^ ((kr0 & 7) << 4);
  int ksrc1 = (c1 * 16) ^ ((kr1 & 7) << 4);
  int vsrc0 = kr0 * (kSPAD * 2) + (((c0 & 7) * 16) ^ ((kr0 & 7) << 4));
  int vsrc1 = kr1 * (kSPAD * 2) + (((c1 & 7) * 16) ^ ((kr1 & 7) << 4));
  // bpermute byte addrs: source lanes lr + 32*(lh&1) and +16
  int a0 = (lr + ((l & 16) << 1)) << 2;
  int a1 = a0 + 64;

#define ISSUE_TILE(buf, t) do {                                              \
    GLOAD16(Kg + (size_t)(t) * 8192 + ksrc0, (char*)lsK[buf] + c0 * 16);     \
    GLOAD16(Kg + (size_t)(t) * 8192 + ksrc1, (char*)lsK[buf] + c1 * 16);     \
    GLOAD16(Vg + (size_t)(t) * 128 + vsrc0,  (char*)lsVt[buf] + c0 * 16);    \
    GLOAD16(Vg + (size_t)(t) * 128 + vsrc1,  (char*)lsVt[buf] + c1 * 16);    \
  } while (0)

  ISSUE_TILE(0, 0);

  for (int t = 0; t < kNT64; ++t) {
    int cur = t & 1;
    __builtin_amdgcn_s_barrier();
    if (t + 1 < kNT64) {
      ISSUE_TILE(cur ^ 1, t + 1);
      asm volatile("s_waitcnt vmcnt(4)" ::: "memory");
    } else {
      asm volatile("s_waitcnt vmcnt(0)" ::: "memory");
    }
    __builtin_amdgcn_s_barrier();
    __builtin_amdgcn_sched_barrier(0);

    // QK^T swapped: s[kb] = K-rows x Q -> S^T[k][q=lr]
    f32x4 s[4] = {};
    __builtin_amdgcn_s_setprio(1);
#pragma unroll
    for (int kk = 0; kk < 2; ++kk) {
#pragma unroll
      for (int kb = 0; kb < 4; ++kb) {
        int row = kb * 16 + lr;
        s16x8 bk8 = *(const s16x8*)((const char*)lsK[cur] +
                      ((row * 128 + kk * 64 + lh * 16) ^ ((lr & 7) << 4)));
        s[kb] = mfma16(bk8, aq[kk], s[kb]);
      }
    }
    __builtin_amdgcn_s_setprio(0);

    if (t == kNT64 - 1) {                  // mask tail k >= kS
      int kv0 = t * 64;
#pragma unroll
      for (int kb = 0; kb < 4; ++kb)
#pragma unroll
        for (int r = 0; r < 4; ++r)
          if (kv0 + kb * 16 + lh * 4 + r >= kS) s[kb][r] = -1e30f;
    }

    // softmax: per-lane partial max; ballot equivalent to full-row check; defer-max THR=8
    float pm = s[0][0];
#pragma unroll
    for (int kb = 0; kb < 4; ++kb)
#pragma unroll
      for (int r = 0; r < 4; ++r) pm = fmaxf(pm, s[kb][r]);
    if (!__all(pm <= m + 8.0f)) {          // rare: full reduce + rescale
      float pmf = fmaxf(pm, __shfl_xor(pm, 16));
      pmf = fmaxf(pmf, __shfl_xor(pmf, 32));
      float nm = fmaxf(m, pmf);
      float al = exp2f(m - nm);
      m = nm;
      lsum *= al;
#pragma unroll
      for (int db = 0; db < 4; ++db)
#pragma unroll
        for (int r = 0; r < 4; ++r) o[db][r] *= al;
    }
#pragma unroll
    for (int kb = 0; kb < 4; ++kb)
#pragma unroll
      for (int r = 0; r < 4; ++r) { s[kb][r] = exp2f(s[kb][r] - m); lsum += s[kb][r]; }

    // pack P to bf16 pairs (lane holds k = kb*16+lh*4+r, q = lr)
    unsigned p01[4], p23[4];
#pragma unroll
    for (int kb = 0; kb < 4; ++kb) {
      p01[kb] = cvt_pk_bf16(s[kb][0], s[kb][1]);
      p23[kb] = cvt_pk_bf16(s[kb][2], s[kb][3]);
    }

    // PV: B-fragment P[q=lr][k'=lh*8+j] built in-register via ds_bpermute
    // target needs {p01,p23}[kb = half*2 + (lh>>1)] from lanes lr+32*(lh&1), +16
#pragma unroll
    for (int half = 0; half < 2; ++half) {
      unsigned uA, uB, pw0, pw1, pw2, pw3;
      uA = (unsigned)__builtin_amdgcn_ds_bpermute(a0, (int)p01[half * 2]);
      uB = (unsigned)__builtin_amdgcn_ds_bpermute(a0, (int)p01[half * 2 + 1]);
      pw0 = (l & 32) ? uB : uA;
      uA = (unsigned)__builtin_amdgcn_ds_bpermute(a0, (int)p23[half * 2]);
      uB = (unsigned)__builtin_amdgcn_ds_bpermute(a0, (int)p23[half * 2 + 1]);
      pw1 = (l & 32) ? uB : uA;
      uA = (unsigned)__builtin_amdgcn_ds_bpermute(a1, (int)p01[half * 2]);
      uB = (unsigned)__builtin_amdgcn_ds_bpermute(a1, (int)p01[half * 2 + 1]);
      pw2 = (l & 32) ? uB : uA;
      uA = (unsigned)__builtin_amdgcn_ds_bpermute(a1, (int)p23[half * 2]);
      uB = (unsigned)__builtin_amdgcn_ds_bpermute(a1, (int)p23[half * 2 + 1]);
      pw3 = (l & 32) ? uB : uA;
      union { unsigned u[4]; s16x8 v; } pu;
      pu.u[0] = pw0; pu.u[1] = pw1; pu.u[2] = pw2; pu.u[3] = pw3;
      s16x8 pa = pu.v;
      __builtin_amdgcn_s_setprio(1);
#pragma unroll
      for (int db = 0; db < 4; ++db) {
        int d = db * 16 + lr;
        s16x8 bv = *(const s16x8*)((const char*)lsVt[cur] +
                     ((d * 128 + half * 64 + lh * 16) ^ ((lr & 7) << 4)));
        o[db] = mfma16(bv, pa, o[db]);
      }
      __builtin_amdgcn_s_setprio(0);
    }
  }
#undef ISSUE_TILE

  // reduce partial lsum across the 4 lanes sharing q-row lr
  lsum += __shfl_xor(lsum, 16);
  lsum += __shfl_xor(lsum, 32);

  int b = bh >> 4, h = bh & 15;
  int srow = q0 + lr;
  if (srow < kS) {
    float inv = 1.0f / lsum;
    size_t base = (size_t)(b * kS + srow) * kD + h * 64;
#pragma unroll
    for (int db = 0; db < 4; ++db)
#pragma unroll
      for (int r = 0; r < 4; ++r)
        AO[base + db * 16 + lh * 4 + r] = f2bf(o[db][r] * inv);
  }
}

// ---------------- launch ----------------
extern "C" void kernel_launch(void* const* d_in, const int* in_sizes, int n_in,
                              void* d_out, int out_size, void* d_ws, size_t ws_size,
                              hipStream_t stream) {
  const float* hid  = (const float*)d_in[0];
  const float* enc  = (const float*)d_in[1];
  const float* cosb = (const float*)d_in[2];
  const float* sinb = (const float*)d_in[3];
  const float* wq   = (const float*)d_in[4];
  const float* bq   = (const float*)d_in[5];
  const float* wk   = (const float*)d_in[6];
  const float* bk   = (const float*)d_in[7];
  const float* wv   = (const float*)d_in[8];
  const float* bv   = (const float*)d_in[9];
  const float* wo   = (const float*)d_in[10];
  const float* bo   = (const float*)d_in[11];
  const float* lnqw = (const float*)d_in[12];
  const float* lnqb = (const float*)d_in[13];
  const float* lnkw = (const float*)d_in[14];
  const float* lnkb = (const float*)d_in[15];

  if (ws_size < 112197632u) return;

  char* ws = (char*)d_ws;
  ushort* Xb   = (ushort*)(ws);                  // [4608][1024] bf16
  ushort* Wqkv = (ushort*)(ws + 9437184);        // [3072][1024] bf16
  ushort* Wo   = (ushort*)(ws + 15728640);       // [1024][1024] bf16
  ushort* Vtb  = (ushort*)(ws + 17825792);       // [32][64][2304] bf16
  ushort* Qb   = (ushort*)(ws + 74448896);       // [32][2304][64] bf16
  ushort* Kb   = (ushort*)(ws + 83886080);       // [32][2304][64] bf16
  ushort* AO   = (ushort*)(ws + 102760448);      // [4608][1024] bf16

  float* out = (float*)d_out;

  k_prep_w<<<dim3(4096), dim3(256), 0, stream>>>(wq, wk, wv, wo, Wqkv, Wo);
  k_prep_x<<<dim3(4668), dim3(256), 0, stream>>>(hid, enc, Xb, AO);
  k_padz<<<dim3(360), dim3(256), 0, stream>>>(Qb, Kb, Vtb);
  k_gemmqkv<<<dim3(36 * 24), dim3(256), 0, stream>>>(Xb, Wqkv, bq, bk, bv,
      lnqw, lnqb, lnkw, lnkb, cosb, sinb, Qb, Kb, Vtb);
  k_attn<<<dim3(32 * 36), dim3(256), 0, stream>>>(Qb, Kb, Vtb, AO);
  k_gemmo<<<dim3(36 * 8), dim3(256), 0, stream>>>(AO, Wo, out, bo);
}